// Round 9
// baseline (414.706 us; speedup 1.0000x reference)
//
#include <hip/hip_runtime.h>
#include <math.h>

#define BATCH 8
#define CCH 20
#define THW 15000
#define HW 625
#define SSIDE 25
#define PHW 729          // 27*27 zero-padded spatial

#define NKEY 15000
#define TPAD 15104      // 59*256, padded key dim
#define NKT 118         // ceil(15000/128) k-tiles of 128
#define NKC 20          // k-chunks of 6 tiles (last gets 4)
#define KCHUNK 6

typedef __attribute__((ext_vector_type(8))) short bf16x8;
typedef __attribute__((ext_vector_type(4))) float f32x4;

// ---- ws layout (byte offsets), NON-ALIASED ----
#define YBF_OFF  0ULL            // 8*729*64*2      = 746,496
#define XA_OFF   746496ULL       // 16*729*256*2    = 5,971,968
#define XB_OFF   6718464ULL      // 16*729*256*2    -> ends 12,690,432
#define WT0_OFF  12690432ULL     // 2*9*256*64*2    = 589,824
#define WT_OFF   13280256ULL     // 6*2*9*256*256*2 = 14,155,776 -> ends 27,436,032
#define WTL_ELEMS 1179648ULL     // 2*9*256*256 ushorts per layer
#define FMT_OFF  27436032ULL     // 8*TPAD*32*2 = 7,733,248
#define FM32_OFF 35169280ULL     // 7,733,248
#define FQB_OFF  42902528ULL     // 327,680
#define PART_OFF 43230208ULL     // 8*5*20*128*48 = 4,915,200 -> ends 48,145,408
#define PC_OFF   48145408ULL     // 2*16*625*256*4 = 20,480,000 -> ends 68,625,408

__device__ __forceinline__ ushort f2bf(float x) {
    unsigned u = __float_as_uint(x);
    u = (u + 0x7FFFu + ((u >> 16) & 1u)) >> 16;
    return (ushort)u;
}
__device__ __forceinline__ float bf2f(ushort v) {
    return __uint_as_float(((unsigned)v) << 16);
}

// direct global->LDS staging (vmcnt-tracked). LDS dest is wave-uniform base;
// HW writes lane*16B linearly from it. Swizzle achieved by per-lane SOURCE.
__device__ __forceinline__ void gload16(const void* g, void* l) {
    __builtin_amdgcn_global_load_lds((const __attribute__((address_space(1))) void*)g,
                                     (__attribute__((address_space(3))) void*)l, 16, 0, 0);
}

// ===== prep: fm -> fmbT (t-major rows of 32 ch) + fmb32 (ch-major), bf16 =====
__global__ __launch_bounds__(256) void prep_fm(const float* __restrict__ fm,
                                               ushort* __restrict__ fmbT,
                                               ushort* __restrict__ fmb32) {
    __shared__ ushort sT2[256][34];
    const int tid = threadIdx.x;
    const int t0 = blockIdx.x * 256;
    const int b = blockIdx.y;
    const int t = t0 + tid;
    #pragma unroll 4
    for (int c = 0; c < CCH; c++) {
        float v = (t < NKEY) ? fm[((size_t)b * CCH + c) * THW + t] : 0.f;
        ushort h = f2bf(v);
        sT2[tid][c] = h;
        fmb32[((size_t)b * 32 + c) * TPAD + t] = h;
    }
    #pragma unroll
    for (int cz = CCH; cz < 32; cz++)
        fmb32[((size_t)b * 32 + cz) * TPAD + t] = 0;
    __syncthreads();
    const int g = tid >> 4, j = tid & 15;
    uint* dstb = (uint*)fmbT + ((size_t)b * TPAD + t0) * 16 + j;
    #pragma unroll
    for (int i = 0; i < 16; i++) {
        int r = g + 16 * i;
        uint v = 0;
        if (j < 10) v = *(const uint*)&sT2[r][2 * j];
        dstb[(size_t)r * 16] = v;
    }
}

// fq -> fqb bf16 [b][640][32], scale 1/sqrt(512)*log2(e) folded
__global__ __launch_bounds__(256) void prep_fq(const float* __restrict__ fq,
                                               ushort* __restrict__ fqb) {
    int idx = blockIdx.x * 256 + threadIdx.x;
    if (idx >= BATCH * 640) return;
    int b = idx / 640, q = idx % 640;
    const float qscale = 1.4426950408889634f * 0.04419417382415922f;
    ushort* dst = fqb + (size_t)idx * 32;
    #pragma unroll 4
    for (int c = 0; c < CCH; c++) {
        float v = (q < HW) ? fq[((size_t)b * CCH + c) * HW + q] * qscale : 0.f;
        dst[c] = f2bf(v);
    }
    #pragma unroll
    for (int c = CCH; c < 32; c++) dst[c] = 0;
}

// ===== MFMA flash attention v3 + XCD swizzle: 1D grid 480, one b per XCD =====
__global__ __launch_bounds__(512) void attn_flash(const ushort* __restrict__ fmbT,
                                                  const ushort* __restrict__ fmb32,
                                                  const ushort* __restrict__ fqb,
                                                  char* __restrict__ part) {
    __shared__ __align__(16) ushort sK[2][4096];  // 128 keys x 32ch, 64B rows, XOR(r&3) @16B
    __shared__ __align__(16) ushort sV[2][4096];  // 32ch x 128 keys, 256B rows, XOR(r&7) @16B
    __shared__ __align__(16) ushort sP[8][2048];  // per-wave 16q x 128k, XOR(q7) on uint bits 3-5
    const int tid = threadIdx.x;
    const int wave = tid >> 6, lane = tid & 63;
    const int q16 = lane & 15, quad = lane >> 4;
    // XCD-chunked remap: 480 blocks, 60 per XCD = all blocks of one b
    const int phys = blockIdx.x;
    const int lid = (phys & 7) * 60 + (phys >> 3);
    const int b = lid / 60;
    const int rem = lid - b * 60;
    const int kc = rem / 3;
    const int xq = rem - kc * 3;
    const int qt0 = xq * 2 + (wave >> 2);
    const bool act = (qt0 < 5);
    const int qt = act ? qt0 : 4;
    const int wq = wave & 3;

    bf16x8 Qf[2];
    #pragma unroll
    for (int nf = 0; nf < 2; nf++)
        Qf[nf] = *(const bf16x8*)(fqb + ((size_t)(b * 640 + qt * 128 + wq * 32 + nf * 16 + q16) << 5) + quad * 8);

    f32x4 O[2][2];
    #pragma unroll
    for (int nf = 0; nf < 2; nf++) { O[nf][0] = (f32x4)0.f; O[nf][1] = (f32x4)0.f; }
    float lp0 = 0.f, lp1 = 0.f;
    const f32x4 zz = (f32x4)0.f;

    const int kt0 = kc * KCHUNK;
    const int kt1 = (kt0 + KCHUNK < NKT) ? kt0 + KCHUNK : NKT;

    // staging: 512 threads x 16B = 8KB each for K and V (2 gloads/thread/kt)
    const int rK = tid >> 2, cK = tid & 3;       // sK: row=key (64B), 4 chunks
    const int rV = tid >> 4, cV = tid & 15;      // sV: row=ch (256B), 16 chunks
    const ushort* srcK = fmbT + ((size_t)(b * TPAD + rK) << 5) + ((cK ^ (rK & 3)) << 3);
    const ushort* srcV = fmb32 + (size_t)(b * 32 + rV) * TPAD + ((cV ^ (rV & 7)) << 3);
    auto stage = [&](int kt, int bufi) {
        const int t0s = kt << 7;
        gload16(srcK + ((size_t)t0s << 5), &sK[bufi][wave << 9]);
        gload16(srcV + t0s, &sV[bufi][wave << 9]);
    };

    // fragment read offsets (swizzled)
    const int q3 = q16 & 3, q7 = q16 & 7;
    uint* const pBase = (uint*)&sP[wave][q16 << 7];

    int buf = 0;
    stage(kt0, 0);
    for (int kt = kt0; kt < kt1; kt++) {
        if (kt + 1 < kt1) {
            stage(kt + 1, buf ^ 1);
            asm volatile("s_waitcnt vmcnt(2)\n\ts_barrier" ::: "memory");
        } else {
            asm volatile("s_waitcnt vmcnt(0)\n\ts_barrier" ::: "memory");
        }
        const int t0 = kt << 7;
        const bool tail = (t0 + 128 > NKEY);

        bf16x8 Ak[8], Av[8];
        #pragma unroll
        for (int m = 0; m < 8; m++)
            Ak[m] = *(const bf16x8*)&sK[buf][((m * 16 + q16) << 5) + ((quad ^ q3) << 3)];
        #pragma unroll
        for (int mp = 0; mp < 4; mp++)
            #pragma unroll
            for (int cf = 0; cf < 2; cf++)
                Av[mp * 2 + cf] = *(const bf16x8*)&sV[buf][((cf * 16 + q16) << 7) + (((mp * 4 + quad) ^ q7) << 3)];

        f32x4 S[8][2];
        #pragma unroll
        for (int m = 0; m < 8; m++) {
            S[m][0] = __builtin_amdgcn_mfma_f32_16x16x32_bf16(Ak[m], Qf[0], zz, 0, 0, 0);
            S[m][1] = __builtin_amdgcn_mfma_f32_16x16x32_bf16(Ak[m], Qf[1], zz, 0, 0, 0);
        }

        #pragma unroll
        for (int nf = 0; nf < 2; nf++) {
            float lacc = 0.f;
            #pragma unroll
            for (int m = 0; m < 8; m++) {
                float p[4];
                #pragma unroll
                for (int i = 0; i < 4; i++) {
                    float v = __builtin_amdgcn_exp2f(S[m][nf][i]);
                    if (tail && (t0 + m * 16 + quad * 4 + i >= NKEY)) v = 0.f;
                    p[i] = v;
                }
                lacc += (p[0] + p[1]) + (p[2] + p[3]);
                uint pk0 = __builtin_amdgcn_perm(__float_as_uint(p[1]) + 0x8000u,
                                                 __float_as_uint(p[0]) + 0x8000u, 0x07060302u);
                uint pk1 = __builtin_amdgcn_perm(__float_as_uint(p[3]) + 0x8000u,
                                                 __float_as_uint(p[2]) + 0x8000u, 0x07060302u);
                uint* dst = pBase + (((m ^ q7) << 3) + quad * 2);
                dst[0] = pk0;
                dst[1] = pk1;
            }
            if (nf == 0) lp0 += lacc; else lp1 += lacc;
            #pragma unroll
            for (int mp = 0; mp < 4; mp++) {
                bf16x8 Bp = *(const bf16x8*)(pBase + ((mp * 16 + quad * 4) ^ (q7 << 3)));
                O[nf][0] = __builtin_amdgcn_mfma_f32_16x16x32_bf16(Av[mp * 2 + 0], Bp, O[nf][0], 0, 0, 0);
                O[nf][1] = __builtin_amdgcn_mfma_f32_16x16x32_bf16(Av[mp * 2 + 1], Bp, O[nf][1], 0, 0, 0);
            }
        }
        asm volatile("s_waitcnt lgkmcnt(0)\n\ts_barrier" ::: "memory");
        buf ^= 1;
    }

    lp0 += __shfl_xor(lp0, 16); lp0 += __shfl_xor(lp0, 32);
    lp1 += __shfl_xor(lp1, 16); lp1 += __shfl_xor(lp1, 32);

    if (act) {
        #pragma unroll
        for (int nf = 0; nf < 2; nf++) {
            int ql = wq * 32 + nf * 16 + q16;
            size_t rec = ((((size_t)b * 5 + qt) * NKC + kc) * 128 + ql) * 48;
            uint2 pk;
            pk.x = (unsigned)f2bf(O[nf][0][0]) | ((unsigned)f2bf(O[nf][0][1]) << 16);
            pk.y = (unsigned)f2bf(O[nf][0][2]) | ((unsigned)f2bf(O[nf][0][3]) << 16);
            *(uint2*)(part + rec + quad * 8) = pk;
            if (quad == 0) {
                uint2 pk1;
                pk1.x = (unsigned)f2bf(O[nf][1][0]) | ((unsigned)f2bf(O[nf][1][1]) << 16);
                pk1.y = (unsigned)f2bf(O[nf][1][2]) | ((unsigned)f2bf(O[nf][1][3]) << 16);
                *(uint2*)(part + rec + 32) = pk1;
                *(float*)(part + rec + 40) = (nf == 0) ? lp0 : lp1;
            }
        }
    }
}

// merge partials -> YBF (blocks 0..19) + zero halo borders (blocks 20..461)
__device__ __forceinline__ int border_pp(int bi) {
    if (bi < 27) return bi;                   // top row
    if (bi < 54) return 26 * 27 + (bi - 27);  // bottom row
    if (bi < 79) return (bi - 53) * 27;       // left col, rows 1..25
    return (bi - 78) * 27 + 26;               // right col, rows 1..25
}
__global__ __launch_bounds__(256) void attn_merge_zero(const char* __restrict__ part,
                                                       const float* __restrict__ fq,
                                                       ushort* __restrict__ ybf,
                                                       ushort* __restrict__ xa,
                                                       ushort* __restrict__ xb) {
    if (blockIdx.x < 20) {
        int g = blockIdx.x * 256 + threadIdx.x;
        if (g >= BATCH * HW) return;
        int b = g / HW, q = g % HW;
        int qt = q >> 7, ql = q & 127;
        const char* pb = part + ((((size_t)b * 5 + qt) * NKC) * 128 + ql) * 48;
        float L = 0.f;
        float acc[CCH];
        #pragma unroll
        for (int c = 0; c < CCH; c++) acc[c] = 0.f;
        for (int kc = 0; kc < NKC; kc++) {
            const char* rec = pb + (size_t)kc * 128 * 48;
            L += *(const float*)(rec + 40);
            const ushort* av = (const ushort*)rec;
            #pragma unroll
            for (int c = 0; c < CCH; c++) acc[c] += bf2f(av[c]);
        }
        float inv = 1.f / L;
        int pp = (q / 25 + 1) * 27 + (q % 25) + 1;
        ushort* yb = ybf + ((size_t)b * PHW + pp) * 64;
        #pragma unroll
        for (int c = 0; c < CCH; c++) yb[c] = f2bf(acc[c] * inv);
        #pragma unroll
        for (int c = 0; c < CCH; c++) yb[20 + c] = f2bf(fq[((size_t)b * CCH + c) * HW + q]);
        #pragma unroll
        for (int c = 40; c < 64; c++) yb[c] = 0;
    } else {
        int idx = (blockIdx.x - 20) * 256 + threadIdx.x;
        ushort* buf; int cin;
        if (idx < 6656) { buf = ybf; cin = 64; }
        else if (idx < 59904) { idx -= 6656; buf = xa; cin = 256; }
        else if (idx < 113152) { idx -= 59904; buf = xb; cin = 256; }
        else return;
        int nc = cin >> 3;
        int per = 104 * nc;
        int img = idx / per, r = idx - img * per;
        int bi = r / nc, cc = r - bi * nc;
        int pp = border_pp(bi);
        uint4 z = make_uint4(0, 0, 0, 0);
        *(uint4*)&buf[((size_t)img * PHW + pp) * cin + cc * 8] = z;
    }
}

// ===== combined weight prep: blocks 0..1151 = w0; 1152.. = wk (512/layer) ====
__global__ __launch_bounds__(256) void prep_weights(const float* __restrict__ cw1,
                                                    const float* __restrict__ rw1,
                                                    const float* __restrict__ cwk,
                                                    const float* __restrict__ rwk,
                                                    ushort* __restrict__ wt0,
                                                    ushort* __restrict__ wt) {
    int bid = blockIdx.x;
    if (bid < 1152) {
        int idx = bid * 256 + threadIdx.x;
        if (idx >= 2 * 9 * 256 * 64) return;
        int ic = idx & 63;
        int oc = (idx >> 6) & 255;
        int t = idx >> 14;
        int kyx = t % 9;
        int br = t / 9;
        float v = 0.f;
        if (ic < 40) {
            const float* w = br ? rw1 : cw1;
            v = w[((size_t)oc * 40 + ic) * 9 + kyx];
        }
        wt0[idx] = f2bf(v);
    } else {
        int rb = bid - 1152;
        int s = rb >> 9;
        int idx = (rb & 511) * 256 + threadIdx.x;
        if (idx >= 2 * 256 * 256) return;
        int ic = idx & 255;
        int oc = (idx >> 8) & 255;
        int br = idx >> 16;
        const float* w = br ? rwk : cwk;
        const float* src = w + (((size_t)s * 256 + oc) * 256 + ic) * 9;
        ushort* dst = wt + (size_t)s * WTL_ELEMS;
        float v[9];
        #pragma unroll
        for (int k = 0; k < 9; k++) v[k] = src[k];
        #pragma unroll
        for (int k = 0; k < 9; k++)
            dst[(((size_t)(br * 9 + k)) * 256 + oc) * 256 + ic] = f2bf(v[k]);
    }
}

// ============ conv layer 1 (cin=64), R5-verified v2 + XCD remap =============
__global__ __launch_bounds__(256) void conv_gemm(
    const ushort* __restrict__ xin, int cin, int cshift, int in_shared, int relu_out,
    const ushort* __restrict__ wt, const float* __restrict__ bias_c,
    const float* __restrict__ bias_r, ushort* __restrict__ xout) {
    __shared__ __align__(16) ushort sA[3][4096];
    __shared__ __align__(16) ushort sB[3][4096];
    const int tid = threadIdx.x;
    const int lane = tid & 63;
    const int wave = tid >> 6;
    const int n16 = lane & 15, quad = lane >> 4;
    const int wm = wave & 1, wn = wave >> 1;
    const int phys = blockIdx.x;
    const int lid = (phys & 7) * 80 + (phys >> 3);
    const int bb = lid / 40;
    const int rr2 = lid - bb * 40;
    const int ot = rr2 & 3, nt = rr2 >> 2;
    const int oc0 = ot * 64;
    const ushort* wbr = wt + (size_t)(bb < 8 ? 0 : 1) * 9 * 256 * cin;
    const float* bias = (bb < 8) ? bias_c : bias_r;
    const ushort* inb = xin + (size_t)(in_shared ? (bb & 7) : bb) * PHW * cin;

    const int l8 = lane >> 3, j8 = lane & 7;
    const int r0 = wave * 16 + l8;
    const int jj = j8 ^ (l8 & 7);
    const int segA = wave * 1024;

    const ushort* aS0 = wbr + (size_t)(oc0 + r0) * cin + jj * 8;
    const ushort* aS1 = aS0 + (size_t)8 * cin;
    const int p0 = nt * 64 + r0;
    const int p1 = p0 + 8;
    const int pe0 = (p0 < HW) ? p0 : (HW - 1);
    const int pe1 = (p1 < HW) ? p1 : (HW - 1);
    const ushort* bS0 = inb + (size_t)((pe0 / 25) * 27 + (pe0 % 25)) * cin + jj * 8;
    const ushort* bS1 = inb + (size_t)((pe1 / 25) * 27 + (pe1 % 25)) * cin + jj * 8;

    const int NIT = 9 << cshift;
    const int cmask = (1 << cshift) - 1;

    auto issue = [&](int it, int buf) {
        const int kyx = it >> cshift;
        const int ccc = it & cmask;
        const int ky = (kyx >= 6) ? 2 : (kyx >= 3 ? 1 : 0);
        const int kx = kyx - ky * 3;
        const int aoff = kyx * 256 * cin + ccc * 64;
        const int boff = (ky * 27 + kx) * cin + ccc * 64;
        gload16(aS0 + aoff, &sA[buf][segA]);
        gload16(aS1 + aoff, &sA[buf][segA + 512]);
        gload16(bS0 + boff, &sB[buf][segA]);
        gload16(bS1 + boff, &sB[buf][segA + 512]);
    };

    f32x4 acc00 = (f32x4)0.f, acc01 = (f32x4)0.f;
    f32x4 acc10 = (f32x4)0.f, acc11 = (f32x4)0.f;
    const int arow0 = wm * 32 + n16;
    const int brow0 = wn * 32 + n16;
    const int h8 = n16 & 7;

    auto mfma_tile = [&](const ushort* sa, const ushort* sb) {
        #pragma unroll
        for (int ks = 0; ks < 2; ks++) {
            const int swz = ((ks * 4 + quad) ^ h8) * 8;
            bf16x8 a0 = *(const bf16x8*)&sa[arow0 * 64 + swz];
            bf16x8 a1 = *(const bf16x8*)&sa[(arow0 + 16) * 64 + swz];
            bf16x8 b0 = *(const bf16x8*)&sb[brow0 * 64 + swz];
            bf16x8 b1 = *(const bf16x8*)&sb[(brow0 + 16) * 64 + swz];
            acc00 = __builtin_amdgcn_mfma_f32_16x16x32_bf16(a0, b0, acc00, 0, 0, 0);
            acc01 = __builtin_amdgcn_mfma_f32_16x16x32_bf16(a0, b1, acc01, 0, 0, 0);
            acc10 = __builtin_amdgcn_mfma_f32_16x16x32_bf16(a1, b0, acc10, 0, 0, 0);
            acc11 = __builtin_amdgcn_mfma_f32_16x16x32_bf16(a1, b1, acc11, 0, 0, 0);
        }
    };

    issue(0, 0);
    issue(1, 1);
    asm volatile("s_waitcnt vmcnt(4)\n\ts_barrier" ::: "memory");

    for (int it = 0; it < NIT; it += 3) {
        const bool nl = (it + 3 < NIT);
        issue(it + 2, 2);
        mfma_tile(sA[0], sB[0]);
        asm volatile("s_waitcnt vmcnt(4)\n\ts_barrier" ::: "memory");
        if (nl) issue(it + 3, 0);
        mfma_tile(sA[1], sB[1]);
        if (nl) {
            asm volatile("s_waitcnt vmcnt(4)\n\ts_barrier" ::: "memory");
            issue(it + 4, 1);
        } else {
            asm volatile("s_waitcnt vmcnt(0)\n\ts_barrier" ::: "memory");
        }
        mfma_tile(sA[2], sB[2]);
        if (nl) asm volatile("s_waitcnt vmcnt(4)\n\ts_barrier" ::: "memory");
    }

    f32x4 accs[2][2] = {{acc00, acc01}, {acc10, acc11}};
    #pragma unroll
    for (int mf = 0; mf < 2; mf++) {
        int ocb = oc0 + wm * 32 + mf * 16 + quad * 4;
        float4 bv = *(const float4*)(bias + ocb);
        #pragma unroll
        for (int nf = 0; nf < 2; nf++) {
            int pcol = nt * 64 + wn * 32 + nf * 16 + n16;
            if (pcol >= HW) continue;
            int pp = (pcol / 25 + 1) * 27 + (pcol % 25) + 1;
            f32x4 a = accs[mf][nf];
            float v0 = a[0] + bv.x;
            float v1 = a[1] + bv.y;
            float v2 = a[2] + bv.z;
            float v3 = a[3] + bv.w;
            if (relu_out) {
                v0 = fmaxf(v0, 0.f); v1 = fmaxf(v1, 0.f);
                v2 = fmaxf(v2, 0.f); v3 = fmaxf(v3, 0.f);
            }
            uint2 st;
            st.x = (unsigned)f2bf(v0) | ((unsigned)f2bf(v1) << 16);
            st.y = (unsigned)f2bf(v2) | ((unsigned)f2bf(v3) << 16);
            *(uint2*)(&xout[((size_t)bb * PHW + pp) * 256 + ocb]) = st;
        }
    }
}

// ===== split-K conv (cin=256): 1280 blocks, kh in {0,1} does 18 of 36 iters,
// writes f32 partials to pc[kh][16][625][256]. Core identical to conv_gemm. ===
__global__ __launch_bounds__(256) void conv_gemm_sk(
    const ushort* __restrict__ xin, const ushort* __restrict__ wt,
    float* __restrict__ pout) {
    __shared__ __align__(16) ushort sA[3][4096];
    __shared__ __align__(16) ushort sB[3][4096];
    const int cin = 256;
    const int tid = threadIdx.x;
    const int lane = tid & 63;
    const int wave = tid >> 6;
    const int n16 = lane & 15, quad = lane >> 4;
    const int wm = wave & 1, wn = wave >> 1;
    // XCD remap over 1280 blocks (160/XCD): kh-major then bb/nt/ot
    const int phys = blockIdx.x;
    const int lid = (phys & 7) * 160 + (phys >> 3);
    const int kh = lid / 640;
    const int l2 = lid - kh * 640;
    const int bb = l2 / 40;
    const int rr2 = l2 - bb * 40;
    const int ot = rr2 & 3, nt = rr2 >> 2;
    const int oc0 = ot * 64;
    const ushort* wbr = wt + (size_t)(bb < 8 ? 0 : 1) * 9 * 256 * cin;
    const ushort* inb = xin + (size_t)bb * PHW * cin;

    const int l8 = lane >> 3, j8 = lane & 7;
    const int r0 = wave * 16 + l8;
    const int jj = j8 ^ (l8 & 7);
    const int segA = wave * 1024;

    const ushort* aS0 = wbr + (size_t)(oc0 + r0) * cin + jj * 8;
    const ushort* aS1 = aS0 + (size_t)8 * cin;
    const int p0 = nt * 64 + r0;
    const int p1 = p0 + 8;
    const int pe0 = (p0 < HW) ? p0 : (HW - 1);
    const int pe1 = (p1 < HW) ? p1 : (HW - 1);
    const ushort* bS0 = inb + (size_t)((pe0 / 25) * 27 + (pe0 % 25)) * cin + jj * 8;
    const ushort* bS1 = inb + (size_t)((pe1 / 25) * 27 + (pe1 % 25)) * cin + jj * 8;

    const int it0 = kh * 18;                   // 18 iters per half (tap-major split)

    auto issue = [&](int it, int buf) {        // absolute it in [it0, it0+18)
        const int kyx = it >> 2;
        const int ccc = it & 3;
        const int ky = (kyx >= 6) ? 2 : (kyx >= 3 ? 1 : 0);
        const int kx = kyx - ky * 3;
        const int aoff = kyx * 256 * cin + ccc * 64;
        const int boff = (ky * 27 + kx) * cin + ccc * 64;
        gload16(aS0 + aoff, &sA[buf][segA]);
        gload16(aS1 + aoff, &sA[buf][segA + 512]);
        gload16(bS0 + boff, &sB[buf][segA]);
        gload16(bS1 + boff, &sB[buf][segA + 512]);
    };

    f32x4 acc00 = (f32x4)0.f, acc01 = (f32x4)0.f;
    f32x4 acc10 = (f32x4)0.f, acc11 = (f32x4)0.f;
    const int arow0 = wm * 32 + n16;
    const int brow0 = wn * 32 + n16;
    const int h8 = n16 & 7;

    auto mfma_tile = [&](const ushort* sa, const ushort* sb) {
        #pragma unroll
        for (int ks = 0; ks < 2; ks++) {
            const int swz = ((ks * 4 + quad) ^ h8) * 8;
            bf16x8 a0 = *(const bf16x8*)&sa[arow0 * 64 + swz];
            bf16x8 a1 = *(const bf16x8*)&sa[(arow0 + 16) * 64 + swz];
            bf16x8 b0 = *(const bf16x8*)&sb[brow0 * 64 + swz];
            bf16x8 b1 = *(const bf16x8*)&sb[(brow0 + 16) * 64 + swz];
            acc00 = __builtin_amdgcn_mfma_f32_16x16x32_bf16(a0, b0, acc00, 0, 0, 0);
            acc01 = __builtin_amdgcn_mfma_f32_16x16x32_bf16(a0, b1, acc01, 0, 0, 0);
            acc10 = __builtin_amdgcn_mfma_f32_16x16x32_bf16(a1, b0, acc10, 0, 0, 0);
            acc11 = __builtin_amdgcn_mfma_f32_16x16x32_bf16(a1, b1, acc11, 0, 0, 0);
        }
    };

    issue(it0 + 0, 0);
    issue(it0 + 1, 1);
    asm volatile("s_waitcnt vmcnt(4)\n\ts_barrier" ::: "memory");

    for (int k = 0; k < 18; k += 3) {
        const bool nl = (k + 3 < 18);
        issue(it0 + k + 2, 2);
        mfma_tile(sA[0], sB[0]);
        asm volatile("s_waitcnt vmcnt(4)\n\ts_barrier" ::: "memory");
        if (nl) issue(it0 + k + 3, 0);
        mfma_tile(sA[1], sB[1]);
        if (nl) {
            asm volatile("s_waitcnt vmcnt(4)\n\ts_barrier" ::: "memory");
            issue(it0 + k + 4, 1);
        } else {
            asm volatile("s_waitcnt vmcnt(0)\n\ts_barrier" ::: "memory");
        }
        mfma_tile(sA[2], sB[2]);
        if (nl) asm volatile("s_waitcnt vmcnt(4)\n\ts_barrier" ::: "memory");
    }

    float* pbase = pout + (size_t)kh * 16 * HW * 256;
    f32x4 accs[2][2] = {{acc00, acc01}, {acc10, acc11}};
    #pragma unroll
    for (int mf = 0; mf < 2; mf++) {
        int ocb = oc0 + wm * 32 + mf * 16 + quad * 4;
        #pragma unroll
        for (int nf = 0; nf < 2; nf++) {
            int pcol = nt * 64 + wn * 32 + nf * 16 + n16;
            if (pcol >= HW) continue;
            f32x4 a = accs[mf][nf];
            *(float4*)(pbase + ((size_t)bb * HW + pcol) * 256 + ocb) =
                make_float4(a[0], a[1], a[2], a[3]);
        }
    }
}

// combine split-K partials: out = bf16(relu(pc0 + pc1 + bias)), padded NHWC
__global__ __launch_bounds__(256) void conv_combine(const float* __restrict__ pc,
                                                    const float* __restrict__ bias_c,
                                                    const float* __restrict__ bias_r,
                                                    int relu_out,
                                                    ushort* __restrict__ xout) {
    int g = blockIdx.x * 256 + threadIdx.x;
    if (g >= 16 * HW * 32) return;
    int oc8 = (g & 31) * 8;
    int rest = g >> 5;
    int p = rest % HW;
    int b = rest / HW;
    size_t i0 = ((size_t)b * HW + p) * 256 + oc8;
    const float* p0 = pc + i0;
    const float* p1 = pc + (size_t)16 * HW * 256 + i0;
    const float* bias = ((b < 8) ? bias_c : bias_r) + oc8;
    float4 x0 = *(const float4*)p0;
    float4 x1 = *(const float4*)(p0 + 4);
    float4 y0 = *(const float4*)p1;
    float4 y1 = *(const float4*)(p1 + 4);
    float4 b0 = *(const float4*)bias;
    float4 b1 = *(const float4*)(bias + 4);
    float v[8];
    v[0] = x0.x + y0.x + b0.x; v[1] = x0.y + y0.y + b0.y;
    v[2] = x0.z + y0.z + b0.z; v[3] = x0.w + y0.w + b0.w;
    v[4] = x1.x + y1.x + b1.x; v[5] = x1.y + y1.y + b1.y;
    v[6] = x1.z + y1.z + b1.z; v[7] = x1.w + y1.w + b1.w;
    if (relu_out) {
        #pragma unroll
        for (int j = 0; j < 8; j++) v[j] = fmaxf(v[j], 0.f);
    }
    uint4 st;
    st.x = (unsigned)f2bf(v[0]) | ((unsigned)f2bf(v[1]) << 16);
    st.y = (unsigned)f2bf(v[2]) | ((unsigned)f2bf(v[3]) << 16);
    st.z = (unsigned)f2bf(v[4]) | ((unsigned)f2bf(v[5]) << 16);
    st.w = (unsigned)f2bf(v[6]) | ((unsigned)f2bf(v[7]) << 16);
    int pp = (p / 25 + 1) * 27 + (p % 25) + 1;
    *(uint4*)&xout[((size_t)b * PHW + pp) * 256 + oc8] = st;
}

// ================= heads =================
__global__ __launch_bounds__(256) void heads(const ushort* __restrict__ X,
                                             const float* __restrict__ wcls, const float* __restrict__ bcls,
                                             const float* __restrict__ gcls, const float* __restrict__ becls,
                                             const float* __restrict__ wctr, const float* __restrict__ bctr,
                                             const float* __restrict__ gctr, const float* __restrict__ bectr,
                                             const float* __restrict__ woff, const float* __restrict__ boff,
                                             const float* __restrict__ goff, const float* __restrict__ beoff,
                                             const float* __restrict__ si, const float* __restrict__ bi,
                                             float* __restrict__ out) {
    int g = blockIdx.x * 256 + threadIdx.x;
    if (g >= BATCH * HW) return;
    int b = g / HW, p = g % HW;
    int pp = (p / 25 + 1) * 27 + (p % 25) + 1;
    const ushort* fc = X + ((size_t)b * PHW + pp) * 256;
    const ushort* fr = X + ((size_t)(8 + b) * PHW + pp) * 256;
    float ac = 0.f, at = 0.f, a0 = 0.f, a1 = 0.f, a2 = 0.f, a3 = 0.f;
    for (int c0 = 0; c0 < 256; c0 += 8) {
        uint4 vc = *(const uint4*)(fc + c0);
        uint4 vr = *(const uint4*)(fr + c0);
        unsigned wc_[4] = {vc.x, vc.y, vc.z, vc.w};
        unsigned wr_[4] = {vr.x, vr.y, vr.z, vr.w};
        #pragma unroll
        for (int j = 0; j < 4; j++) {
            float cl = __uint_as_float(wc_[j] << 16);
            float ch = __uint_as_float(wc_[j] & 0xFFFF0000u);
            float rl = __uint_as_float(wr_[j] << 16);
            float rh = __uint_as_float(wr_[j] & 0xFFFF0000u);
            int c = c0 + j * 2;
            ac += wcls[c] * cl + wcls[c + 1] * ch;
            at += wctr[c] * cl + wctr[c + 1] * ch;
            a0 += woff[c] * rl + woff[c + 1] * rh;
            a1 += woff[256 + c] * rl + woff[256 + c + 1] * rh;
            a2 += woff[512 + c] * rl + woff[512 + c + 1] * rh;
            a3 += woff[768 + c] * rl + woff[768 + c + 1] * rh;
        }
    }
    const float bns = 1.f / sqrtf(1.f + 1e-5f);
    float cls = (ac + bcls[0]) * (gcls[0] * bns) + becls[0];
    float ctr = (at + bctr[0]) * (gctr[0] * bns) + bectr[0];
    float sv = si[0], bv = bi[0];
    float o0 = (a0 + boff[0]) * (goff[0] * bns) + beoff[0];
    float o1 = (a1 + boff[1]) * (goff[1] * bns) + beoff[1];
    float o2 = (a2 + boff[2]) * (goff[2] * bns) + beoff[2];
    float o3 = (a3 + boff[3]) * (goff[3] * bns) + beoff[3];
    float e0 = __expf(sv * o0 + bv) * 8.f;
    float e1 = __expf(sv * o1 + bv) * 8.f;
    float e2 = __expf(sv * o2 + bv) * 8.f;
    float e3 = __expf(sv * o3 + bv) * 8.f;
    float gx = 3.f + 8.f * (float)(p % SSIDE);
    float gy = 3.f + 8.f * (float)(p / SSIDE);
    out[g] = cls;
    out[BATCH * HW + g] = ctr;
    float* bbx = out + 2 * BATCH * HW + (size_t)g * 4;
    bbx[0] = gx - e0;
    bbx[1] = gy - e1;
    bbx[2] = gx + e2;
    bbx[3] = gy + e3;
}

extern "C" void kernel_launch(void* const* d_in, const int* in_sizes, int n_in,
                              void* d_out, int out_size, void* d_ws, size_t ws_size,
                              hipStream_t stream) {
    const float* fm     = (const float*)d_in[0];
    const float* fq     = (const float*)d_in[1];
    const float* cls1_w = (const float*)d_in[2];
    const float* cls1_b = (const float*)d_in[3];
    const float* clsk_w = (const float*)d_in[4];
    const float* clsk_b = (const float*)d_in[5];
    const float* reg1_w = (const float*)d_in[6];
    const float* reg1_b = (const float*)d_in[7];
    const float* regk_w = (const float*)d_in[8];
    const float* regk_b = (const float*)d_in[9];
    const float* w_cls  = (const float*)d_in[10];
    const float* b_cls  = (const float*)d_in[11];
    const float* g_cls  = (const float*)d_in[12];
    const float* be_cls = (const float*)d_in[13];
    const float* w_ctr  = (const float*)d_in[14];
    const float* b_ctr  = (const float*)d_in[15];
    const float* g_ctr  = (const float*)d_in[16];
    const float* be_ctr = (const float*)d_in[17];
    const float* w_off  = (const float*)d_in[18];
    const float* b_off  = (const float*)d_in[19];
    const float* g_off  = (const float*)d_in[20];
    const float* be_off = (const float*)d_in[21];
    const float* si     = (const float*)d_in[22];
    const float* bi     = (const float*)d_in[23];

    char* ws = (char*)d_ws;
    ushort* YBF  = (ushort*)(ws + YBF_OFF);
    ushort* XA   = (ushort*)(ws + XA_OFF);
    ushort* XB   = (ushort*)(ws + XB_OFF);
    ushort* WT0  = (ushort*)(ws + WT0_OFF);
    ushort* WT   = (ushort*)(ws + WT_OFF);
    ushort* FMT  = (ushort*)(ws + FMT_OFF);
    ushort* FM32 = (ushort*)(ws + FM32_OFF);
    ushort* FQB  = (ushort*)(ws + FQB_OFF);
    char*   PART = ws + PART_OFF;
    float*  PC   = (float*)(ws + PC_OFF);

    // --- attention ---
    prep_fm<<<dim3(59, 8), 256, 0, stream>>>(fm, FMT, FM32);
    prep_fq<<<dim3(20), 256, 0, stream>>>(fq, FQB);
    attn_flash<<<dim3(480), 512, 0, stream>>>(FMT, FM32, FQB, PART);
    attn_merge_zero<<<dim3(462), 256, 0, stream>>>(PART, fq, YBF, XA, XB);

    // --- weight prep (one launch) ---
    prep_weights<<<dim3(1152 + 512 * 6), 256, 0, stream>>>(cls1_w, reg1_w, clsk_w, regk_w, WT0, WT);

    // --- conv tower ---
    conv_gemm<<<dim3(640), 256, 0, stream>>>(YBF, 64, 0, 1, 1, WT0, cls1_b, reg1_b, XA);

    ushort* cur = XA;
    ushort* nxt = XB;
    for (int s = 0; s < 6; s++) {
        int relu_out = (s < 5) ? 1 : 0;
        conv_gemm_sk<<<dim3(1280), 256, 0, stream>>>(cur, WT + (size_t)s * WTL_ELEMS, PC);
        conv_combine<<<dim3(1250), 256, 0, stream>>>(PC, clsk_b + (size_t)s * 256,
                                                     regk_b + (size_t)s * 256, relu_out, nxt);
        ushort* tmp = cur; cur = nxt; nxt = tmp;
    }

    heads<<<dim3(20), 256, 0, stream>>>(cur, w_cls, b_cls, g_cls, be_cls,
                                        w_ctr, b_ctr, g_ctr, be_ctr,
                                        w_off, b_off, g_off, be_off, si, bi,
                                        (float*)d_out);
}

// Round 10
// 365.506 us; speedup vs baseline: 1.1346x; 1.1346x over previous
//
#include <hip/hip_runtime.h>
#include <math.h>

#define BATCH 8
#define CCH 20
#define THW 15000
#define HW 625
#define SSIDE 25
#define PHW 729          // 27*27 zero-padded spatial

#define NKEY 15000
#define TPAD 15104      // 59*256, padded key dim
#define NKT 118         // ceil(15000/128) k-tiles of 128
#define NKC 20          // k-chunks of 6 tiles (last gets 4)
#define KCHUNK 6

typedef __attribute__((ext_vector_type(8))) short bf16x8;
typedef __attribute__((ext_vector_type(4))) float f32x4;

// ---- ws layout (byte offsets), NON-ALIASED ----
#define YBF_OFF  0ULL            // 8*729*64*2      = 746,496
#define XA_OFF   746496ULL       // 16*729*256*2    = 5,971,968
#define XB_OFF   6718464ULL      // 16*729*256*2    -> ends 12,690,432
#define WT0_OFF  12690432ULL     // 2*9*256*64*2    = 589,824
#define WT_OFF   13280256ULL     // 6*2*9*256*256*2 = 14,155,776 -> ends 27,436,032
#define WTL_ELEMS 1179648ULL     // 2*9*256*256 ushorts per layer
#define FMT_OFF  27436032ULL     // 8*TPAD*32*2 = 7,733,248
#define FM32_OFF 35169280ULL     // 7,733,248
#define FQB_OFF  42902528ULL     // 327,680
#define PART_OFF 43230208ULL     // 8*5*20*128*48 = 4,915,200 -> ends 48,145,408

__device__ __forceinline__ ushort f2bf(float x) {
    unsigned u = __float_as_uint(x);
    u = (u + 0x7FFFu + ((u >> 16) & 1u)) >> 16;
    return (ushort)u;
}
__device__ __forceinline__ float bf2f(ushort v) {
    return __uint_as_float(((unsigned)v) << 16);
}

// direct global->LDS staging (vmcnt-tracked). LDS dest is wave-uniform base;
// HW writes lane*16B linearly from it. Swizzle achieved by per-lane SOURCE.
__device__ __forceinline__ void gload16(const void* g, void* l) {
    __builtin_amdgcn_global_load_lds((const __attribute__((address_space(1))) void*)g,
                                     (__attribute__((address_space(3))) void*)l, 16, 0, 0);
}

// ===== prep: fm -> fmbT (t-major rows of 32 ch) + fmb32 (ch-major), bf16 =====
__global__ __launch_bounds__(256) void prep_fm(const float* __restrict__ fm,
                                               ushort* __restrict__ fmbT,
                                               ushort* __restrict__ fmb32) {
    __shared__ ushort sT2[256][34];
    const int tid = threadIdx.x;
    const int t0 = blockIdx.x * 256;
    const int b = blockIdx.y;
    const int t = t0 + tid;
    #pragma unroll 4
    for (int c = 0; c < CCH; c++) {
        float v = (t < NKEY) ? fm[((size_t)b * CCH + c) * THW + t] : 0.f;
        ushort h = f2bf(v);
        sT2[tid][c] = h;
        fmb32[((size_t)b * 32 + c) * TPAD + t] = h;
    }
    #pragma unroll
    for (int cz = CCH; cz < 32; cz++)
        fmb32[((size_t)b * 32 + cz) * TPAD + t] = 0;
    __syncthreads();
    const int g = tid >> 4, j = tid & 15;
    uint* dstb = (uint*)fmbT + ((size_t)b * TPAD + t0) * 16 + j;
    #pragma unroll
    for (int i = 0; i < 16; i++) {
        int r = g + 16 * i;
        uint v = 0;
        if (j < 10) v = *(const uint*)&sT2[r][2 * j];
        dstb[(size_t)r * 16] = v;
    }
}

// fq -> fqb bf16 [b][640][32], scale 1/sqrt(512)*log2(e) folded
__global__ __launch_bounds__(256) void prep_fq(const float* __restrict__ fq,
                                               ushort* __restrict__ fqb) {
    int idx = blockIdx.x * 256 + threadIdx.x;
    if (idx >= BATCH * 640) return;
    int b = idx / 640, q = idx % 640;
    const float qscale = 1.4426950408889634f * 0.04419417382415922f;
    ushort* dst = fqb + (size_t)idx * 32;
    #pragma unroll 4
    for (int c = 0; c < CCH; c++) {
        float v = (q < HW) ? fq[((size_t)b * CCH + c) * HW + q] * qscale : 0.f;
        dst[c] = f2bf(v);
    }
    #pragma unroll
    for (int c = CCH; c < 32; c++) dst[c] = 0;
}

// ===== MFMA flash attention v3 + XCD swizzle: 1D grid 480, one b per XCD =====
__global__ __launch_bounds__(512) void attn_flash(const ushort* __restrict__ fmbT,
                                                  const ushort* __restrict__ fmb32,
                                                  const ushort* __restrict__ fqb,
                                                  char* __restrict__ part) {
    __shared__ __align__(16) ushort sK[2][4096];  // 128 keys x 32ch, 64B rows, XOR(r&3) @16B
    __shared__ __align__(16) ushort sV[2][4096];  // 32ch x 128 keys, 256B rows, XOR(r&7) @16B
    __shared__ __align__(16) ushort sP[8][2048];  // per-wave 16q x 128k, XOR(q7) on uint bits 3-5
    const int tid = threadIdx.x;
    const int wave = tid >> 6, lane = tid & 63;
    const int q16 = lane & 15, quad = lane >> 4;
    // XCD-chunked remap: 480 blocks, 60 per XCD = all blocks of one b
    const int phys = blockIdx.x;
    const int lid = (phys & 7) * 60 + (phys >> 3);
    const int b = lid / 60;
    const int rem = lid - b * 60;
    const int kc = rem / 3;
    const int xq = rem - kc * 3;
    const int qt0 = xq * 2 + (wave >> 2);
    const bool act = (qt0 < 5);
    const int qt = act ? qt0 : 4;
    const int wq = wave & 3;

    bf16x8 Qf[2];
    #pragma unroll
    for (int nf = 0; nf < 2; nf++)
        Qf[nf] = *(const bf16x8*)(fqb + ((size_t)(b * 640 + qt * 128 + wq * 32 + nf * 16 + q16) << 5) + quad * 8);

    f32x4 O[2][2];
    #pragma unroll
    for (int nf = 0; nf < 2; nf++) { O[nf][0] = (f32x4)0.f; O[nf][1] = (f32x4)0.f; }
    float lp0 = 0.f, lp1 = 0.f;
    const f32x4 zz = (f32x4)0.f;

    const int kt0 = kc * KCHUNK;
    const int kt1 = (kt0 + KCHUNK < NKT) ? kt0 + KCHUNK : NKT;

    // staging: 512 threads x 16B = 8KB each for K and V (2 gloads/thread/kt)
    const int rK = tid >> 2, cK = tid & 3;       // sK: row=key (64B), 4 chunks
    const int rV = tid >> 4, cV = tid & 15;      // sV: row=ch (256B), 16 chunks
    const ushort* srcK = fmbT + ((size_t)(b * TPAD + rK) << 5) + ((cK ^ (rK & 3)) << 3);
    const ushort* srcV = fmb32 + (size_t)(b * 32 + rV) * TPAD + ((cV ^ (rV & 7)) << 3);
    auto stage = [&](int kt, int bufi) {
        const int t0s = kt << 7;
        gload16(srcK + ((size_t)t0s << 5), &sK[bufi][wave << 9]);
        gload16(srcV + t0s, &sV[bufi][wave << 9]);
    };

    // fragment read offsets (swizzled)
    const int q3 = q16 & 3, q7 = q16 & 7;
    uint* const pBase = (uint*)&sP[wave][q16 << 7];

    int buf = 0;
    stage(kt0, 0);
    for (int kt = kt0; kt < kt1; kt++) {
        if (kt + 1 < kt1) {
            stage(kt + 1, buf ^ 1);
            asm volatile("s_waitcnt vmcnt(2)\n\ts_barrier" ::: "memory");
        } else {
            asm volatile("s_waitcnt vmcnt(0)\n\ts_barrier" ::: "memory");
        }
        const int t0 = kt << 7;
        const bool tail = (t0 + 128 > NKEY);

        bf16x8 Ak[8], Av[8];
        #pragma unroll
        for (int m = 0; m < 8; m++)
            Ak[m] = *(const bf16x8*)&sK[buf][((m * 16 + q16) << 5) + ((quad ^ q3) << 3)];
        #pragma unroll
        for (int mp = 0; mp < 4; mp++)
            #pragma unroll
            for (int cf = 0; cf < 2; cf++)
                Av[mp * 2 + cf] = *(const bf16x8*)&sV[buf][((cf * 16 + q16) << 7) + (((mp * 4 + quad) ^ q7) << 3)];

        f32x4 S[8][2];
        #pragma unroll
        for (int m = 0; m < 8; m++) {
            S[m][0] = __builtin_amdgcn_mfma_f32_16x16x32_bf16(Ak[m], Qf[0], zz, 0, 0, 0);
            S[m][1] = __builtin_amdgcn_mfma_f32_16x16x32_bf16(Ak[m], Qf[1], zz, 0, 0, 0);
        }

        #pragma unroll
        for (int nf = 0; nf < 2; nf++) {
            float lacc = 0.f;
            #pragma unroll
            for (int m = 0; m < 8; m++) {
                float p[4];
                #pragma unroll
                for (int i = 0; i < 4; i++) {
                    float v = __builtin_amdgcn_exp2f(S[m][nf][i]);
                    if (tail && (t0 + m * 16 + quad * 4 + i >= NKEY)) v = 0.f;
                    p[i] = v;
                }
                lacc += (p[0] + p[1]) + (p[2] + p[3]);
                uint pk0 = __builtin_amdgcn_perm(__float_as_uint(p[1]) + 0x8000u,
                                                 __float_as_uint(p[0]) + 0x8000u, 0x07060302u);
                uint pk1 = __builtin_amdgcn_perm(__float_as_uint(p[3]) + 0x8000u,
                                                 __float_as_uint(p[2]) + 0x8000u, 0x07060302u);
                uint* dst = pBase + (((m ^ q7) << 3) + quad * 2);
                dst[0] = pk0;
                dst[1] = pk1;
            }
            if (nf == 0) lp0 += lacc; else lp1 += lacc;
            #pragma unroll
            for (int mp = 0; mp < 4; mp++) {
                bf16x8 Bp = *(const bf16x8*)(pBase + ((mp * 16 + quad * 4) ^ (q7 << 3)));
                O[nf][0] = __builtin_amdgcn_mfma_f32_16x16x32_bf16(Av[mp * 2 + 0], Bp, O[nf][0], 0, 0, 0);
                O[nf][1] = __builtin_amdgcn_mfma_f32_16x16x32_bf16(Av[mp * 2 + 1], Bp, O[nf][1], 0, 0, 0);
            }
        }
        asm volatile("s_waitcnt lgkmcnt(0)\n\ts_barrier" ::: "memory");
        buf ^= 1;
    }

    lp0 += __shfl_xor(lp0, 16); lp0 += __shfl_xor(lp0, 32);
    lp1 += __shfl_xor(lp1, 16); lp1 += __shfl_xor(lp1, 32);

    if (act) {
        #pragma unroll
        for (int nf = 0; nf < 2; nf++) {
            int ql = wq * 32 + nf * 16 + q16;
            size_t rec = ((((size_t)b * 5 + qt) * NKC + kc) * 128 + ql) * 48;
            uint2 pk;
            pk.x = (unsigned)f2bf(O[nf][0][0]) | ((unsigned)f2bf(O[nf][0][1]) << 16);
            pk.y = (unsigned)f2bf(O[nf][0][2]) | ((unsigned)f2bf(O[nf][0][3]) << 16);
            *(uint2*)(part + rec + quad * 8) = pk;
            if (quad == 0) {
                uint2 pk1;
                pk1.x = (unsigned)f2bf(O[nf][1][0]) | ((unsigned)f2bf(O[nf][1][1]) << 16);
                pk1.y = (unsigned)f2bf(O[nf][1][2]) | ((unsigned)f2bf(O[nf][1][3]) << 16);
                *(uint2*)(part + rec + 32) = pk1;
                *(float*)(part + rec + 40) = (nf == 0) ? lp0 : lp1;
            }
        }
    }
}

// merge partials -> YBF (blocks 0..19) + zero halo borders (blocks 20..461)
__device__ __forceinline__ int border_pp(int bi) {
    if (bi < 27) return bi;                   // top row
    if (bi < 54) return 26 * 27 + (bi - 27);  // bottom row
    if (bi < 79) return (bi - 53) * 27;       // left col, rows 1..25
    return (bi - 78) * 27 + 26;               // right col, rows 1..25
}
__global__ __launch_bounds__(256) void attn_merge_zero(const char* __restrict__ part,
                                                       const float* __restrict__ fq,
                                                       ushort* __restrict__ ybf,
                                                       ushort* __restrict__ xa,
                                                       ushort* __restrict__ xb) {
    if (blockIdx.x < 20) {
        int g = blockIdx.x * 256 + threadIdx.x;
        if (g >= BATCH * HW) return;
        int b = g / HW, q = g % HW;
        int qt = q >> 7, ql = q & 127;
        const char* pb = part + ((((size_t)b * 5 + qt) * NKC) * 128 + ql) * 48;
        float L = 0.f;
        float acc[CCH];
        #pragma unroll
        for (int c = 0; c < CCH; c++) acc[c] = 0.f;
        for (int kc = 0; kc < NKC; kc++) {
            const char* rec = pb + (size_t)kc * 128 * 48;
            L += *(const float*)(rec + 40);
            const ushort* av = (const ushort*)rec;
            #pragma unroll
            for (int c = 0; c < CCH; c++) acc[c] += bf2f(av[c]);
        }
        float inv = 1.f / L;
        int pp = (q / 25 + 1) * 27 + (q % 25) + 1;
        ushort* yb = ybf + ((size_t)b * PHW + pp) * 64;
        #pragma unroll
        for (int c = 0; c < CCH; c++) yb[c] = f2bf(acc[c] * inv);
        #pragma unroll
        for (int c = 0; c < CCH; c++) yb[20 + c] = f2bf(fq[((size_t)b * CCH + c) * HW + q]);
        #pragma unroll
        for (int c = 40; c < 64; c++) yb[c] = 0;
    } else {
        int idx = (blockIdx.x - 20) * 256 + threadIdx.x;
        ushort* buf; int cin;
        if (idx < 6656) { buf = ybf; cin = 64; }
        else if (idx < 59904) { idx -= 6656; buf = xa; cin = 256; }
        else if (idx < 113152) { idx -= 59904; buf = xb; cin = 256; }
        else return;
        int nc = cin >> 3;
        int per = 104 * nc;
        int img = idx / per, r = idx - img * per;
        int bi = r / nc, cc = r - bi * nc;
        int pp = border_pp(bi);
        uint4 z = make_uint4(0, 0, 0, 0);
        *(uint4*)&buf[((size_t)img * PHW + pp) * cin + cc * 8] = z;
    }
}

// ===== combined weight prep: blocks 0..1151 = w0; 1152.. = wk (512/layer) ====
__global__ __launch_bounds__(256) void prep_weights(const float* __restrict__ cw1,
                                                    const float* __restrict__ rw1,
                                                    const float* __restrict__ cwk,
                                                    const float* __restrict__ rwk,
                                                    ushort* __restrict__ wt0,
                                                    ushort* __restrict__ wt) {
    int bid = blockIdx.x;
    if (bid < 1152) {
        int idx = bid * 256 + threadIdx.x;
        if (idx >= 2 * 9 * 256 * 64) return;
        int ic = idx & 63;
        int oc = (idx >> 6) & 255;
        int t = idx >> 14;
        int kyx = t % 9;
        int br = t / 9;
        float v = 0.f;
        if (ic < 40) {
            const float* w = br ? rw1 : cw1;
            v = w[((size_t)oc * 40 + ic) * 9 + kyx];
        }
        wt0[idx] = f2bf(v);
    } else {
        int rb = bid - 1152;
        int s = rb >> 9;
        int idx = (rb & 511) * 256 + threadIdx.x;
        if (idx >= 2 * 256 * 256) return;
        int ic = idx & 255;
        int oc = (idx >> 8) & 255;
        int br = idx >> 16;
        const float* w = br ? rwk : cwk;
        const float* src = w + (((size_t)s * 256 + oc) * 256 + ic) * 9;
        ushort* dst = wt + (size_t)s * WTL_ELEMS;
        float v[9];
        #pragma unroll
        for (int k = 0; k < 9; k++) v[k] = src[k];
        #pragma unroll
        for (int k = 0; k < 9; k++)
            dst[(((size_t)(br * 9 + k)) * 256 + oc) * 256 + ic] = f2bf(v[k]);
    }
}

// ====== implicit-im2col GEMM conv, 64x64 tile, DOUBLE-buffer (32KB LDS) ======
// v5: 2 LDS buffers -> 5 blocks/CU (was 3 at 48KB). Prefetch iter t+1 issued
// BEFORE iter t's MFMA (ds_read+MFMA time covers most of the L2 latency);
// one vmcnt(0)+barrier per iter, stall hidden by 5-deep block TLP.
__global__ __launch_bounds__(256) void conv_gemm(
    const ushort* __restrict__ xin, int cin, int cshift, int in_shared, int relu_out,
    const ushort* __restrict__ wt, const float* __restrict__ bias_c,
    const float* __restrict__ bias_r, ushort* __restrict__ xout) {
    __shared__ __align__(16) ushort sA[2][4096];
    __shared__ __align__(16) ushort sB[2][4096];
    const int tid = threadIdx.x;
    const int lane = tid & 63;
    const int wave = tid >> 6;
    const int n16 = lane & 15, quad = lane >> 4;
    const int wm = wave & 1, wn = wave >> 1;
    // XCD-chunked remap (640 % 8 == 0, bijective)
    const int phys = blockIdx.x;
    const int lid = (phys & 7) * 80 + (phys >> 3);
    const int bb = lid / 40;
    const int rr2 = lid - bb * 40;
    const int ot = rr2 & 3, nt = rr2 >> 2;
    const int oc0 = ot * 64;
    const ushort* wbr = wt + (size_t)(bb < 8 ? 0 : 1) * 9 * 256 * cin;
    const float* bias = (bb < 8) ? bias_c : bias_r;
    const ushort* inb = xin + (size_t)(in_shared ? (bb & 7) : bb) * PHW * cin;

    const int l8 = lane >> 3, j8 = lane & 7;
    const int r0 = wave * 16 + l8;
    const int jj = j8 ^ (l8 & 7);
    const int segA = wave * 1024;

    const ushort* aS0 = wbr + (size_t)(oc0 + r0) * cin + jj * 8;
    const ushort* aS1 = aS0 + (size_t)8 * cin;
    const int p0 = nt * 64 + r0;
    const int p1 = p0 + 8;
    const int pe0 = (p0 < HW) ? p0 : (HW - 1);
    const int pe1 = (p1 < HW) ? p1 : (HW - 1);
    const ushort* bS0 = inb + (size_t)((pe0 / 25) * 27 + (pe0 % 25)) * cin + jj * 8;
    const ushort* bS1 = inb + (size_t)((pe1 / 25) * 27 + (pe1 % 25)) * cin + jj * 8;

    const int NIT = 9 << cshift;
    const int cmask = (1 << cshift) - 1;

    auto issue = [&](int it, int buf) {
        const int kyx = it >> cshift;
        const int ccc = it & cmask;
        const int ky = (kyx >= 6) ? 2 : (kyx >= 3 ? 1 : 0);
        const int kx = kyx - ky * 3;
        const int aoff = kyx * 256 * cin + ccc * 64;
        const int boff = (ky * 27 + kx) * cin + ccc * 64;  // top-left base + tap
        gload16(aS0 + aoff, &sA[buf][segA]);
        gload16(aS1 + aoff, &sA[buf][segA + 512]);
        gload16(bS0 + boff, &sB[buf][segA]);
        gload16(bS1 + boff, &sB[buf][segA + 512]);
    };

    f32x4 acc00 = (f32x4)0.f, acc01 = (f32x4)0.f;
    f32x4 acc10 = (f32x4)0.f, acc11 = (f32x4)0.f;
    const int arow0 = wm * 32 + n16;
    const int brow0 = wn * 32 + n16;
    const int h8 = n16 & 7;

    auto mfma_tile = [&](const ushort* sa, const ushort* sb) {
        #pragma unroll
        for (int ks = 0; ks < 2; ks++) {
            const int swz = ((ks * 4 + quad) ^ h8) * 8;
            bf16x8 a0 = *(const bf16x8*)&sa[arow0 * 64 + swz];
            bf16x8 a1 = *(const bf16x8*)&sa[(arow0 + 16) * 64 + swz];
            bf16x8 b0 = *(const bf16x8*)&sb[brow0 * 64 + swz];
            bf16x8 b1 = *(const bf16x8*)&sb[(brow0 + 16) * 64 + swz];
            acc00 = __builtin_amdgcn_mfma_f32_16x16x32_bf16(a0, b0, acc00, 0, 0, 0);
            acc01 = __builtin_amdgcn_mfma_f32_16x16x32_bf16(a0, b1, acc01, 0, 0, 0);
            acc10 = __builtin_amdgcn_mfma_f32_16x16x32_bf16(a1, b0, acc10, 0, 0, 0);
            acc11 = __builtin_amdgcn_mfma_f32_16x16x32_bf16(a1, b1, acc11, 0, 0, 0);
        }
    };

    issue(0, 0);
    asm volatile("s_waitcnt vmcnt(0)\n\ts_barrier" ::: "memory");

    for (int it = 0; it < NIT; it++) {
        if (it + 1 < NIT) issue(it + 1, (it + 1) & 1);
        mfma_tile(sA[it & 1], sB[it & 1]);
        asm volatile("s_waitcnt vmcnt(0) lgkmcnt(0)\n\ts_barrier" ::: "memory");
    }

    f32x4 accs[2][2] = {{acc00, acc01}, {acc10, acc11}};
    #pragma unroll
    for (int mf = 0; mf < 2; mf++) {
        int ocb = oc0 + wm * 32 + mf * 16 + quad * 4;
        float4 bv = *(const float4*)(bias + ocb);
        #pragma unroll
        for (int nf = 0; nf < 2; nf++) {
            int pcol = nt * 64 + wn * 32 + nf * 16 + n16;
            if (pcol >= HW) continue;
            int pp = (pcol / 25 + 1) * 27 + (pcol % 25) + 1;
            f32x4 a = accs[mf][nf];
            float v0 = a[0] + bv.x;
            float v1 = a[1] + bv.y;
            float v2 = a[2] + bv.z;
            float v3 = a[3] + bv.w;
            if (relu_out) {
                v0 = fmaxf(v0, 0.f); v1 = fmaxf(v1, 0.f);
                v2 = fmaxf(v2, 0.f); v3 = fmaxf(v3, 0.f);
            }
            uint2 st;
            st.x = (unsigned)f2bf(v0) | ((unsigned)f2bf(v1) << 16);
            st.y = (unsigned)f2bf(v2) | ((unsigned)f2bf(v3) << 16);
            *(uint2*)(&xout[((size_t)bb * PHW + pp) * 256 + ocb]) = st;
        }
    }
}

// ================= heads =================
__global__ __launch_bounds__(256) void heads(const ushort* __restrict__ X,
                                             const float* __restrict__ wcls, const float* __restrict__ bcls,
                                             const float* __restrict__ gcls, const float* __restrict__ becls,
                                             const float* __restrict__ wctr, const float* __restrict__ bctr,
                                             const float* __restrict__ gctr, const float* __restrict__ bectr,
                                             const float* __restrict__ woff, const float* __restrict__ boff,
                                             const float* __restrict__ goff, const float* __restrict__ beoff,
                                             const float* __restrict__ si, const float* __restrict__ bi,
                                             float* __restrict__ out) {
    int g = blockIdx.x * 256 + threadIdx.x;
    if (g >= BATCH * HW) return;
    int b = g / HW, p = g % HW;
    int pp = (p / 25 + 1) * 27 + (p % 25) + 1;
    const ushort* fc = X + ((size_t)b * PHW + pp) * 256;
    const ushort* fr = X + ((size_t)(8 + b) * PHW + pp) * 256;
    float ac = 0.f, at = 0.f, a0 = 0.f, a1 = 0.f, a2 = 0.f, a3 = 0.f;
    for (int c0 = 0; c0 < 256; c0 += 8) {
        uint4 vc = *(const uint4*)(fc + c0);
        uint4 vr = *(const uint4*)(fr + c0);
        unsigned wc_[4] = {vc.x, vc.y, vc.z, vc.w};
        unsigned wr_[4] = {vr.x, vr.y, vr.z, vr.w};
        #pragma unroll
        for (int j = 0; j < 4; j++) {
            float cl = __uint_as_float(wc_[j] << 16);
            float ch = __uint_as_float(wc_[j] & 0xFFFF0000u);
            float rl = __uint_as_float(wr_[j] << 16);
            float rh = __uint_as_float(wr_[j] & 0xFFFF0000u);
            int c = c0 + j * 2;
            ac += wcls[c] * cl + wcls[c + 1] * ch;
            at += wctr[c] * cl + wctr[c + 1] * ch;
            a0 += woff[c] * rl + woff[c + 1] * rh;
            a1 += woff[256 + c] * rl + woff[256 + c + 1] * rh;
            a2 += woff[512 + c] * rl + woff[512 + c + 1] * rh;
            a3 += woff[768 + c] * rl + woff[768 + c + 1] * rh;
        }
    }
    const float bns = 1.f / sqrtf(1.f + 1e-5f);
    float cls = (ac + bcls[0]) * (gcls[0] * bns) + becls[0];
    float ctr = (at + bctr[0]) * (gctr[0] * bns) + bectr[0];
    float sv = si[0], bv = bi[0];
    float o0 = (a0 + boff[0]) * (goff[0] * bns) + beoff[0];
    float o1 = (a1 + boff[1]) * (goff[1] * bns) + beoff[1];
    float o2 = (a2 + boff[2]) * (goff[2] * bns) + beoff[2];
    float o3 = (a3 + boff[3]) * (goff[3] * bns) + beoff[3];
    float e0 = __expf(sv * o0 + bv) * 8.f;
    float e1 = __expf(sv * o1 + bv) * 8.f;
    float e2 = __expf(sv * o2 + bv) * 8.f;
    float e3 = __expf(sv * o3 + bv) * 8.f;
    float gx = 3.f + 8.f * (float)(p % SSIDE);
    float gy = 3.f + 8.f * (float)(p / SSIDE);
    out[g] = cls;
    out[BATCH * HW + g] = ctr;
    float* bbx = out + 2 * BATCH * HW + (size_t)g * 4;
    bbx[0] = gx - e0;
    bbx[1] = gy - e1;
    bbx[2] = gx + e2;
    bbx[3] = gy + e3;
}

extern "C" void kernel_launch(void* const* d_in, const int* in_sizes, int n_in,
                              void* d_out, int out_size, void* d_ws, size_t ws_size,
                              hipStream_t stream) {
    const float* fm     = (const float*)d_in[0];
    const float* fq     = (const float*)d_in[1];
    const float* cls1_w = (const float*)d_in[2];
    const float* cls1_b = (const float*)d_in[3];
    const float* clsk_w = (const float*)d_in[4];
    const float* clsk_b = (const float*)d_in[5];
    const float* reg1_w = (const float*)d_in[6];
    const float* reg1_b = (const float*)d_in[7];
    const float* regk_w = (const float*)d_in[8];
    const float* regk_b = (const float*)d_in[9];
    const float* w_cls  = (const float*)d_in[10];
    const float* b_cls  = (const float*)d_in[11];
    const float* g_cls  = (const float*)d_in[12];
    const float* be_cls = (const float*)d_in[13];
    const float* w_ctr  = (const float*)d_in[14];
    const float* b_ctr  = (const float*)d_in[15];
    const float* g_ctr  = (const float*)d_in[16];
    const float* be_ctr = (const float*)d_in[17];
    const float* w_off  = (const float*)d_in[18];
    const float* b_off  = (const float*)d_in[19];
    const float* g_off  = (const float*)d_in[20];
    const float* be_off = (const float*)d_in[21];
    const float* si     = (const float*)d_in[22];
    const float* bi     = (const float*)d_in[23];

    char* ws = (char*)d_ws;
    ushort* YBF  = (ushort*)(ws + YBF_OFF);
    ushort* XA   = (ushort*)(ws + XA_OFF);
    ushort* XB   = (ushort*)(ws + XB_OFF);
    ushort* WT0  = (ushort*)(ws + WT0_OFF);
    ushort* WT   = (ushort*)(ws + WT_OFF);
    ushort* FMT  = (ushort*)(ws + FMT_OFF);
    ushort* FM32 = (ushort*)(ws + FM32_OFF);
    ushort* FQB  = (ushort*)(ws + FQB_OFF);
    char*   PART = ws + PART_OFF;

    // --- attention ---
    prep_fm<<<dim3(59, 8), 256, 0, stream>>>(fm, FMT, FM32);
    prep_fq<<<dim3(20), 256, 0, stream>>>(fq, FQB);
    attn_flash<<<dim3(480), 512, 0, stream>>>(FMT, FM32, FQB, PART);
    attn_merge_zero<<<dim3(462), 256, 0, stream>>>(PART, fq, YBF, XA, XB);

    // --- weight prep (one launch) ---
    prep_weights<<<dim3(1152 + 512 * 6), 256, 0, stream>>>(cls1_w, reg1_w, clsk_w, regk_w, WT0, WT);

    // --- conv tower: 1D grid 640 with XCD-chunked remap ---
    conv_gemm<<<dim3(640), 256, 0, stream>>>(YBF, 64, 0, 1, 1, WT0, cls1_b, reg1_b, XA);

    ushort* cur = XA;
    ushort* nxt = XB;
    for (int s = 0; s < 6; s++) {
        int relu_out = (s < 5) ? 1 : 0;
        conv_gemm<<<dim3(640), 256, 0, stream>>>(cur, 256, 2, 0, relu_out,
            WT + (size_t)s * WTL_ELEMS,
            clsk_b + (size_t)s * 256, regk_b + (size_t)s * 256, nxt);
        ushort* tmp = cur; cur = nxt; nxt = tmp;
    }

    heads<<<dim3(20), 256, 0, stream>>>(cur, w_cls, b_cls, g_cls, be_cls,
                                        w_ctr, b_ctr, g_ctr, be_ctr,
                                        w_off, b_off, g_off, be_off, si, bi,
                                        (float*)d_out);
}

// Round 11
// 346.888 us; speedup vs baseline: 1.1955x; 1.0537x over previous
//
#include <hip/hip_runtime.h>
#include <math.h>

#define BATCH 8
#define CCH 20
#define THW 15000
#define HW 625
#define SSIDE 25
#define PHW 729          // 27*27 zero-padded spatial

#define NKEY 15000
#define TPAD 15104      // 59*256, padded key dim
#define NKT 118         // ceil(15000/128) k-tiles of 128
#define NKC 20          // k-chunks of 6 tiles (last gets 4)
#define KCHUNK 6

typedef __attribute__((ext_vector_type(8))) short bf16x8;
typedef __attribute__((ext_vector_type(4))) float f32x4;

// ---- ws layout (byte offsets), NON-ALIASED ----
#define YBF_OFF  0ULL            // 8*729*64*2      = 746,496
#define XA_OFF   746496ULL       // 16*729*256*2    = 5,971,968
#define XB_OFF   6718464ULL      // 16*729*256*2    -> ends 12,690,432
#define WT0_OFF  12690432ULL     // 2*9*256*64*2    = 589,824
#define WT_OFF   13280256ULL     // 6*2*9*256*256*2 = 14,155,776 -> ends 27,436,032
#define WTL_ELEMS 1179648ULL     // 2*9*256*256 ushorts per layer
#define FMT_OFF  27436032ULL     // 8*TPAD*32*2 = 7,733,248
#define FM32_OFF 35169280ULL     // 7,733,248
#define FQB_OFF  42902528ULL     // 327,680
#define PART_OFF 43230208ULL     // 8*5*20*128*48 = 4,915,200 -> ends 48,145,408

__device__ __forceinline__ ushort f2bf(float x) {
    unsigned u = __float_as_uint(x);
    u = (u + 0x7FFFu + ((u >> 16) & 1u)) >> 16;
    return (ushort)u;
}
__device__ __forceinline__ float bf2f(ushort v) {
    return __uint_as_float(((unsigned)v) << 16);
}

// direct global->LDS staging (vmcnt-tracked). LDS dest is wave-uniform base;
// HW writes lane*16B linearly from it. Swizzle achieved by per-lane SOURCE.
__device__ __forceinline__ void gload16(const void* g, void* l) {
    __builtin_amdgcn_global_load_lds((const __attribute__((address_space(1))) void*)g,
                                     (__attribute__((address_space(3))) void*)l, 16, 0, 0);
}

// ===== prep: fm -> fmbT (t-major rows of 32 ch) + fmb32 (ch-major), bf16 =====
__global__ __launch_bounds__(256) void prep_fm(const float* __restrict__ fm,
                                               ushort* __restrict__ fmbT,
                                               ushort* __restrict__ fmb32) {
    __shared__ ushort sT2[256][34];
    const int tid = threadIdx.x;
    const int t0 = blockIdx.x * 256;
    const int b = blockIdx.y;
    const int t = t0 + tid;
    #pragma unroll 4
    for (int c = 0; c < CCH; c++) {
        float v = (t < NKEY) ? fm[((size_t)b * CCH + c) * THW + t] : 0.f;
        ushort h = f2bf(v);
        sT2[tid][c] = h;
        fmb32[((size_t)b * 32 + c) * TPAD + t] = h;
    }
    #pragma unroll
    for (int cz = CCH; cz < 32; cz++)
        fmb32[((size_t)b * 32 + cz) * TPAD + t] = 0;
    __syncthreads();
    const int g = tid >> 4, j = tid & 15;
    uint* dstb = (uint*)fmbT + ((size_t)b * TPAD + t0) * 16 + j;
    #pragma unroll
    for (int i = 0; i < 16; i++) {
        int r = g + 16 * i;
        uint v = 0;
        if (j < 10) v = *(const uint*)&sT2[r][2 * j];
        dstb[(size_t)r * 16] = v;
    }
}

// fq -> fqb bf16 [b][640][32], scale 1/sqrt(512)*log2(e) folded
__global__ __launch_bounds__(256) void prep_fq(const float* __restrict__ fq,
                                               ushort* __restrict__ fqb) {
    int idx = blockIdx.x * 256 + threadIdx.x;
    if (idx >= BATCH * 640) return;
    int b = idx / 640, q = idx % 640;
    const float qscale = 1.4426950408889634f * 0.04419417382415922f;
    ushort* dst = fqb + (size_t)idx * 32;
    #pragma unroll 4
    for (int c = 0; c < CCH; c++) {
        float v = (q < HW) ? fq[((size_t)b * CCH + c) * HW + q] * qscale : 0.f;
        dst[c] = f2bf(v);
    }
    #pragma unroll
    for (int c = CCH; c < 32; c++) dst[c] = 0;
}

// ===== MFMA flash attention v3 + XCD swizzle: 1D grid 480, one b per XCD =====
__global__ __launch_bounds__(512) void attn_flash(const ushort* __restrict__ fmbT,
                                                  const ushort* __restrict__ fmb32,
                                                  const ushort* __restrict__ fqb,
                                                  char* __restrict__ part) {
    __shared__ __align__(16) ushort sK[2][4096];  // 128 keys x 32ch, 64B rows, XOR(r&3) @16B
    __shared__ __align__(16) ushort sV[2][4096];  // 32ch x 128 keys, 256B rows, XOR(r&7) @16B
    __shared__ __align__(16) ushort sP[8][2048];  // per-wave 16q x 128k, XOR(q7) on uint bits 3-5
    const int tid = threadIdx.x;
    const int wave = tid >> 6, lane = tid & 63;
    const int q16 = lane & 15, quad = lane >> 4;
    // XCD-chunked remap: 480 blocks, 60 per XCD = all blocks of one b
    const int phys = blockIdx.x;
    const int lid = (phys & 7) * 60 + (phys >> 3);
    const int b = lid / 60;
    const int rem = lid - b * 60;
    const int kc = rem / 3;
    const int xq = rem - kc * 3;
    const int qt0 = xq * 2 + (wave >> 2);
    const bool act = (qt0 < 5);
    const int qt = act ? qt0 : 4;
    const int wq = wave & 3;

    bf16x8 Qf[2];
    #pragma unroll
    for (int nf = 0; nf < 2; nf++)
        Qf[nf] = *(const bf16x8*)(fqb + ((size_t)(b * 640 + qt * 128 + wq * 32 + nf * 16 + q16) << 5) + quad * 8);

    f32x4 O[2][2];
    #pragma unroll
    for (int nf = 0; nf < 2; nf++) { O[nf][0] = (f32x4)0.f; O[nf][1] = (f32x4)0.f; }
    float lp0 = 0.f, lp1 = 0.f;
    const f32x4 zz = (f32x4)0.f;

    const int kt0 = kc * KCHUNK;
    const int kt1 = (kt0 + KCHUNK < NKT) ? kt0 + KCHUNK : NKT;

    // staging: 512 threads x 16B = 8KB each for K and V (2 gloads/thread/kt)
    const int rK = tid >> 2, cK = tid & 3;       // sK: row=key (64B), 4 chunks
    const int rV = tid >> 4, cV = tid & 15;      // sV: row=ch (256B), 16 chunks
    const ushort* srcK = fmbT + ((size_t)(b * TPAD + rK) << 5) + ((cK ^ (rK & 3)) << 3);
    const ushort* srcV = fmb32 + (size_t)(b * 32 + rV) * TPAD + ((cV ^ (rV & 7)) << 3);
    auto stage = [&](int kt, int bufi) {
        const int t0s = kt << 7;
        gload16(srcK + ((size_t)t0s << 5), &sK[bufi][wave << 9]);
        gload16(srcV + t0s, &sV[bufi][wave << 9]);
    };

    // fragment read offsets (swizzled)
    const int q3 = q16 & 3, q7 = q16 & 7;
    uint* const pBase = (uint*)&sP[wave][q16 << 7];

    int buf = 0;
    stage(kt0, 0);
    for (int kt = kt0; kt < kt1; kt++) {
        if (kt + 1 < kt1) {
            stage(kt + 1, buf ^ 1);
            asm volatile("s_waitcnt vmcnt(2)\n\ts_barrier" ::: "memory");
        } else {
            asm volatile("s_waitcnt vmcnt(0)\n\ts_barrier" ::: "memory");
        }
        const int t0 = kt << 7;
        const bool tail = (t0 + 128 > NKEY);

        bf16x8 Ak[8], Av[8];
        #pragma unroll
        for (int m = 0; m < 8; m++)
            Ak[m] = *(const bf16x8*)&sK[buf][((m * 16 + q16) << 5) + ((quad ^ q3) << 3)];
        #pragma unroll
        for (int mp = 0; mp < 4; mp++)
            #pragma unroll
            for (int cf = 0; cf < 2; cf++)
                Av[mp * 2 + cf] = *(const bf16x8*)&sV[buf][((cf * 16 + q16) << 7) + (((mp * 4 + quad) ^ q7) << 3)];

        f32x4 S[8][2];
        #pragma unroll
        for (int m = 0; m < 8; m++) {
            S[m][0] = __builtin_amdgcn_mfma_f32_16x16x32_bf16(Ak[m], Qf[0], zz, 0, 0, 0);
            S[m][1] = __builtin_amdgcn_mfma_f32_16x16x32_bf16(Ak[m], Qf[1], zz, 0, 0, 0);
        }

        #pragma unroll
        for (int nf = 0; nf < 2; nf++) {
            float lacc = 0.f;
            #pragma unroll
            for (int m = 0; m < 8; m++) {
                float p[4];
                #pragma unroll
                for (int i = 0; i < 4; i++) {
                    float v = __builtin_amdgcn_exp2f(S[m][nf][i]);
                    if (tail && (t0 + m * 16 + quad * 4 + i >= NKEY)) v = 0.f;
                    p[i] = v;
                }
                lacc += (p[0] + p[1]) + (p[2] + p[3]);
                uint pk0 = __builtin_amdgcn_perm(__float_as_uint(p[1]) + 0x8000u,
                                                 __float_as_uint(p[0]) + 0x8000u, 0x07060302u);
                uint pk1 = __builtin_amdgcn_perm(__float_as_uint(p[3]) + 0x8000u,
                                                 __float_as_uint(p[2]) + 0x8000u, 0x07060302u);
                uint* dst = pBase + (((m ^ q7) << 3) + quad * 2);
                dst[0] = pk0;
                dst[1] = pk1;
            }
            if (nf == 0) lp0 += lacc; else lp1 += lacc;
            #pragma unroll
            for (int mp = 0; mp < 4; mp++) {
                bf16x8 Bp = *(const bf16x8*)(pBase + ((mp * 16 + quad * 4) ^ (q7 << 3)));
                O[nf][0] = __builtin_amdgcn_mfma_f32_16x16x32_bf16(Av[mp * 2 + 0], Bp, O[nf][0], 0, 0, 0);
                O[nf][1] = __builtin_amdgcn_mfma_f32_16x16x32_bf16(Av[mp * 2 + 1], Bp, O[nf][1], 0, 0, 0);
            }
        }
        asm volatile("s_waitcnt lgkmcnt(0)\n\ts_barrier" ::: "memory");
        buf ^= 1;
    }

    lp0 += __shfl_xor(lp0, 16); lp0 += __shfl_xor(lp0, 32);
    lp1 += __shfl_xor(lp1, 16); lp1 += __shfl_xor(lp1, 32);

    if (act) {
        #pragma unroll
        for (int nf = 0; nf < 2; nf++) {
            int ql = wq * 32 + nf * 16 + q16;
            size_t rec = ((((size_t)b * 5 + qt) * NKC + kc) * 128 + ql) * 48;
            uint2 pk;
            pk.x = (unsigned)f2bf(O[nf][0][0]) | ((unsigned)f2bf(O[nf][0][1]) << 16);
            pk.y = (unsigned)f2bf(O[nf][0][2]) | ((unsigned)f2bf(O[nf][0][3]) << 16);
            *(uint2*)(part + rec + quad * 8) = pk;
            if (quad == 0) {
                uint2 pk1;
                pk1.x = (unsigned)f2bf(O[nf][1][0]) | ((unsigned)f2bf(O[nf][1][1]) << 16);
                pk1.y = (unsigned)f2bf(O[nf][1][2]) | ((unsigned)f2bf(O[nf][1][3]) << 16);
                *(uint2*)(part + rec + 32) = pk1;
                *(float*)(part + rec + 40) = (nf == 0) ? lp0 : lp1;
            }
        }
    }
}

// merge partials -> YBF (blocks 0..19) + zero halo borders (blocks 20..461)
__device__ __forceinline__ int border_pp(int bi) {
    if (bi < 27) return bi;                   // top row
    if (bi < 54) return 26 * 27 + (bi - 27);  // bottom row
    if (bi < 79) return (bi - 53) * 27;       // left col, rows 1..25
    return (bi - 78) * 27 + 26;               // right col, rows 1..25
}
__global__ __launch_bounds__(256) void attn_merge_zero(const char* __restrict__ part,
                                                       const float* __restrict__ fq,
                                                       ushort* __restrict__ ybf,
                                                       ushort* __restrict__ xa,
                                                       ushort* __restrict__ xb) {
    if (blockIdx.x < 20) {
        int g = blockIdx.x * 256 + threadIdx.x;
        if (g >= BATCH * HW) return;
        int b = g / HW, q = g % HW;
        int qt = q >> 7, ql = q & 127;
        const char* pb = part + ((((size_t)b * 5 + qt) * NKC) * 128 + ql) * 48;
        float L = 0.f;
        float acc[CCH];
        #pragma unroll
        for (int c = 0; c < CCH; c++) acc[c] = 0.f;
        for (int kc = 0; kc < NKC; kc++) {
            const char* rec = pb + (size_t)kc * 128 * 48;
            L += *(const float*)(rec + 40);
            const ushort* av = (const ushort*)rec;
            #pragma unroll
            for (int c = 0; c < CCH; c++) acc[c] += bf2f(av[c]);
        }
        float inv = 1.f / L;
        int pp = (q / 25 + 1) * 27 + (q % 25) + 1;
        ushort* yb = ybf + ((size_t)b * PHW + pp) * 64;
        #pragma unroll
        for (int c = 0; c < CCH; c++) yb[c] = f2bf(acc[c] * inv);
        #pragma unroll
        for (int c = 0; c < CCH; c++) yb[20 + c] = f2bf(fq[((size_t)b * CCH + c) * HW + q]);
        #pragma unroll
        for (int c = 40; c < 64; c++) yb[c] = 0;
    } else {
        int idx = (blockIdx.x - 20) * 256 + threadIdx.x;
        ushort* buf; int cin;
        if (idx < 6656) { buf = ybf; cin = 64; }
        else if (idx < 59904) { idx -= 6656; buf = xa; cin = 256; }
        else if (idx < 113152) { idx -= 59904; buf = xb; cin = 256; }
        else return;
        int nc = cin >> 3;
        int per = 104 * nc;
        int img = idx / per, r = idx - img * per;
        int bi = r / nc, cc = r - bi * nc;
        int pp = border_pp(bi);
        uint4 z = make_uint4(0, 0, 0, 0);
        *(uint4*)&buf[((size_t)img * PHW + pp) * cin + cc * 8] = z;
    }
}

// ===== combined weight prep: blocks 0..1151 = w0; 1152.. = wk (512/layer) ====
__global__ __launch_bounds__(256) void prep_weights(const float* __restrict__ cw1,
                                                    const float* __restrict__ rw1,
                                                    const float* __restrict__ cwk,
                                                    const float* __restrict__ rwk,
                                                    ushort* __restrict__ wt0,
                                                    ushort* __restrict__ wt) {
    int bid = blockIdx.x;
    if (bid < 1152) {
        int idx = bid * 256 + threadIdx.x;
        if (idx >= 2 * 9 * 256 * 64) return;
        int ic = idx & 63;
        int oc = (idx >> 6) & 255;
        int t = idx >> 14;
        int kyx = t % 9;
        int br = t / 9;
        float v = 0.f;
        if (ic < 40) {
            const float* w = br ? rw1 : cw1;
            v = w[((size_t)oc * 40 + ic) * 9 + kyx];
        }
        wt0[idx] = f2bf(v);
    } else {
        int rb = bid - 1152;
        int s = rb >> 9;
        int idx = (rb & 511) * 256 + threadIdx.x;
        if (idx >= 2 * 256 * 256) return;
        int ic = idx & 255;
        int oc = (idx >> 8) & 255;
        int br = idx >> 16;
        const float* w = br ? rwk : cwk;
        const float* src = w + (((size_t)s * 256 + oc) * 256 + ic) * 9;
        ushort* dst = wt + (size_t)s * WTL_ELEMS;
        float v[9];
        #pragma unroll
        for (int k = 0; k < 9; k++) v[k] = src[k];
        #pragma unroll
        for (int k = 0; k < 9; k++)
            dst[(((size_t)(br * 9 + k)) * 256 + oc) * 256 + ic] = f2bf(v[k]);
    }
}

// ======= implicit-im2col GEMM conv v6: B-HALO reuse (R2-verified math) =======
// B staged ONCE per 64-ch chunk as 128-row padded halo (all 9 taps read it
// with compile-time row shift). A double-buffered, per-tap prefetch with
// counted vmcnt; halo for chunk c+1 prefetched 1 load/tap at taps 0-3.
// LDS 48KB -> 3 blocks/CU. Per-XCD L2 traffic 46 -> 29 MB/layer.
__global__ __launch_bounds__(256) void conv_gemm(
    const ushort* __restrict__ xin, int cin, int in_shared, int relu_out,
    const ushort* __restrict__ wt, const float* __restrict__ bias_c,
    const float* __restrict__ bias_r, ushort* __restrict__ xout) {
    __shared__ __align__(16) ushort sA[2][4096];   // 2 x 8KB weight tiles
    __shared__ __align__(16) ushort sBh[2][8192];  // 2 x 16KB halo (128 rows x 64ch)
    const int tid = threadIdx.x;
    const int lane = tid & 63;
    const int wave = tid >> 6;
    const int n16 = lane & 15, quad = lane >> 4;
    const int wm = wave & 1, wn = wave >> 1;
    // XCD-chunked remap (640 % 8 == 0, bijective)
    const int phys = blockIdx.x;
    const int lid = (phys & 7) * 80 + (phys >> 3);
    const int bb = lid / 40;
    const int rr2 = lid - bb * 40;
    const int ot = rr2 & 3, nt = rr2 >> 2;
    const int oc0 = ot * 64;
    const ushort* wbr = wt + (size_t)(bb < 8 ? 0 : 1) * 9 * 256 * cin;
    const float* bias = (bb < 8) ? bias_c : bias_r;
    const ushort* inb = xin + (size_t)(in_shared ? (bb & 7) : bb) * PHW * cin;

    const int l8 = lane >> 3, j8 = lane & 7;
    const int jj = j8 ^ l8;                    // source chunk swizzle (dest r&7 == l8)

    // A staging: wave w owns oc rows [w*16, w*16+16) as two 1KB segments
    const int rA = wave * 16 + l8;
    const ushort* aS0 = wbr + (size_t)(oc0 + rA) * cin + jj * 8;
    const ushort* aS1 = aS0 + (size_t)8 * cin;
    const int segA = wave * 1024;

    // B halo staging: padded base row ppb = pp(p0)-28; thread covers 4 rows
    const int p0 = nt * 64;
    const int ppb = p0 + 2 * (p0 / 25);        // == pp(p0) - 28
    const ushort* bS = inb + (size_t)ppb * cin + jj * 8;

    const int NCH = cin >> 6;                  // 64-ch chunks (1 or 4)

    auto issueA = [&](int ch, int kyx, int buf) {    // 2 loads
        const int aoff = kyx * 256 * cin + ch * 64;
        gload16(aS0 + aoff, &sA[buf][segA]);
        gload16(aS1 + aoff, &sA[buf][segA + 512]);
    };
    auto issueB1 = [&](int ch, int q, int buf) {     // 1 load (1/4 of halo)
        const int rb = (wave * 4 + q) * 8;
        gload16(bS + (size_t)(rb + l8) * cin + ch * 64, &sBh[buf][rb * 64]);
    };

    f32x4 acc00 = (f32x4)0.f, acc01 = (f32x4)0.f;
    f32x4 acc10 = (f32x4)0.f, acc11 = (f32x4)0.f;
    const int arow0 = wm * 32 + n16;
    const int h8 = n16 & 7;
    const int pos0 = p0 + wn * 32 + n16;
    const int pos1 = pos0 + 16;
    const int PR0 = pos0 + 28 + 2 * (pos0 / 25) - ppb;   // halo row of center tap
    const int PR1 = pos1 + 28 + 2 * (pos1 / 25) - ppb;

    auto mfma_tap = [&](const ushort* sa, const ushort* sbh, int d) {
        const int row0 = PR0 + d, row1 = PR1 + d;
        const int m0 = row0 & 7, m1 = row1 & 7;
        #pragma unroll
        for (int ks = 0; ks < 2; ks++) {
            const int cq = ks * 4 + quad;
            bf16x8 a0 = *(const bf16x8*)&sa[arow0 * 64 + ((cq ^ h8) << 3)];
            bf16x8 a1 = *(const bf16x8*)&sa[(arow0 + 16) * 64 + ((cq ^ h8) << 3)];
            bf16x8 b0 = *(const bf16x8*)&sbh[row0 * 64 + ((cq ^ m0) << 3)];
            bf16x8 b1 = *(const bf16x8*)&sbh[row1 * 64 + ((cq ^ m1) << 3)];
            acc00 = __builtin_amdgcn_mfma_f32_16x16x32_bf16(a0, b0, acc00, 0, 0, 0);
            acc01 = __builtin_amdgcn_mfma_f32_16x16x32_bf16(a0, b1, acc01, 0, 0, 0);
            acc10 = __builtin_amdgcn_mfma_f32_16x16x32_bf16(a1, b0, acc10, 0, 0, 0);
            acc11 = __builtin_amdgcn_mfma_f32_16x16x32_bf16(a1, b1, acc11, 0, 0, 0);
        }
    };

    // prologue: halo chunk 0 (4 loads) + A(0,0) (2 loads), drain all
    issueB1(0, 0, 0); issueB1(0, 1, 0); issueB1(0, 2, 0); issueB1(0, 3, 0);
    issueA(0, 0, 0);
    asm volatile("s_waitcnt vmcnt(0)\n\ts_barrier" ::: "memory");

    int itg = 0;
    for (int c = 0; c < NCH; c++) {
        #pragma unroll
        for (int kyx = 0; kyx < 9; kyx++, itg++) {
            if (itg + 1 < NCH * 9) {
                const int nk = (kyx == 8) ? 0 : kyx + 1;
                const int nc = (kyx == 8) ? c + 1 : c;
                issueA(nc, nk, (itg + 1) & 1);
            }
            const bool bpf = (kyx < 4) && (c + 1 < NCH);
            if (bpf) issueB1(c + 1, kyx, (c + 1) & 1);
            const int ky = kyx / 3, kx = kyx % 3;
            mfma_tap(sA[itg & 1], sBh[c & 1], (ky - 1) * 27 + (kx - 1));
            // wait: A(next) must land; one B-halo load may stay in flight
            if (bpf) asm volatile("s_waitcnt vmcnt(1)\n\ts_barrier" ::: "memory");
            else     asm volatile("s_waitcnt vmcnt(0)\n\ts_barrier" ::: "memory");
        }
    }

    f32x4 accs[2][2] = {{acc00, acc01}, {acc10, acc11}};
    #pragma unroll
    for (int mf = 0; mf < 2; mf++) {
        int ocb = oc0 + wm * 32 + mf * 16 + quad * 4;
        float4 bv = *(const float4*)(bias + ocb);
        #pragma unroll
        for (int nf = 0; nf < 2; nf++) {
            int pcol = nt * 64 + wn * 32 + nf * 16 + n16;
            if (pcol >= HW) continue;
            int pp = (pcol / 25 + 1) * 27 + (pcol % 25) + 1;
            f32x4 a = accs[mf][nf];
            float v0 = a[0] + bv.x;
            float v1 = a[1] + bv.y;
            float v2 = a[2] + bv.z;
            float v3 = a[3] + bv.w;
            if (relu_out) {
                v0 = fmaxf(v0, 0.f); v1 = fmaxf(v1, 0.f);
                v2 = fmaxf(v2, 0.f); v3 = fmaxf(v3, 0.f);
            }
            uint2 st;
            st.x = (unsigned)f2bf(v0) | ((unsigned)f2bf(v1) << 16);
            st.y = (unsigned)f2bf(v2) | ((unsigned)f2bf(v3) << 16);
            *(uint2*)(&xout[((size_t)bb * PHW + pp) * 256 + ocb]) = st;
        }
    }
}

// ===== heads v2: 4-way channel split per output, wave handles 16 outputs =====
__global__ __launch_bounds__(256) void heads(const ushort* __restrict__ X,
                                             const float* __restrict__ wcls, const float* __restrict__ bcls,
                                             const float* __restrict__ gcls, const float* __restrict__ becls,
                                             const float* __restrict__ wctr, const float* __restrict__ bctr,
                                             const float* __restrict__ gctr, const float* __restrict__ bectr,
                                             const float* __restrict__ woff, const float* __restrict__ boff,
                                             const float* __restrict__ goff, const float* __restrict__ beoff,
                                             const float* __restrict__ si, const float* __restrict__ bi,
                                             float* __restrict__ out) {
    const int lane = threadIdx.x & 63, wave = threadIdx.x >> 6;
    const int gw = blockIdx.x * 4 + wave;
    const int g = gw * 16 + (lane & 15);
    const int quad = lane >> 4;
    const bool valid = (g < BATCH * HW);
    const int gc = valid ? g : (BATCH * HW - 1);
    const int b = gc / HW, p = gc % HW;
    const int pp = (p / 25 + 1) * 27 + (p % 25) + 1;
    const ushort* fc = X + ((size_t)b * PHW + pp) * 256 + quad * 64;
    const ushort* fr = X + ((size_t)(8 + b) * PHW + pp) * 256 + quad * 64;
    float ac = 0.f, at = 0.f, a0 = 0.f, a1 = 0.f, a2 = 0.f, a3 = 0.f;
    #pragma unroll
    for (int c0 = 0; c0 < 64; c0 += 8) {
        uint4 vc = *(const uint4*)(fc + c0);
        uint4 vr = *(const uint4*)(fr + c0);
        unsigned wc_[4] = {vc.x, vc.y, vc.z, vc.w};
        unsigned wr_[4] = {vr.x, vr.y, vr.z, vr.w};
        #pragma unroll
        for (int j = 0; j < 4; j++) {
            float cl = __uint_as_float(wc_[j] << 16);
            float ch = __uint_as_float(wc_[j] & 0xFFFF0000u);
            float rl = __uint_as_float(wr_[j] << 16);
            float rh = __uint_as_float(wr_[j] & 0xFFFF0000u);
            int c = quad * 64 + c0 + j * 2;
            ac += wcls[c] * cl + wcls[c + 1] * ch;
            at += wctr[c] * cl + wctr[c + 1] * ch;
            a0 += woff[c] * rl + woff[c + 1] * rh;
            a1 += woff[256 + c] * rl + woff[256 + c + 1] * rh;
            a2 += woff[512 + c] * rl + woff[512 + c + 1] * rh;
            a3 += woff[768 + c] * rl + woff[768 + c + 1] * rh;
        }
    }
    // reduce across the 4 channel-quarters (lanes with same lane&15)
    ac += __shfl_xor(ac, 16); at += __shfl_xor(at, 16);
    a0 += __shfl_xor(a0, 16); a1 += __shfl_xor(a1, 16);
    a2 += __shfl_xor(a2, 16); a3 += __shfl_xor(a3, 16);
    ac += __shfl_xor(ac, 32); at += __shfl_xor(at, 32);
    a0 += __shfl_xor(a0, 32); a1 += __shfl_xor(a1, 32);
    a2 += __shfl_xor(a2, 32); a3 += __shfl_xor(a3, 32);
    if (quad == 0 && valid) {
        const float bns = 1.f / sqrtf(1.f + 1e-5f);
        float cls = (ac + bcls[0]) * (gcls[0] * bns) + becls[0];
        float ctr = (at + bctr[0]) * (gctr[0] * bns) + bectr[0];
        float sv = si[0], bv = bi[0];
        float o0 = (a0 + boff[0]) * (goff[0] * bns) + beoff[0];
        float o1 = (a1 + boff[1]) * (goff[1] * bns) + beoff[1];
        float o2 = (a2 + boff[2]) * (goff[2] * bns) + beoff[2];
        float o3 = (a3 + boff[3]) * (goff[3] * bns) + beoff[3];
        float e0 = __expf(sv * o0 + bv) * 8.f;
        float e1 = __expf(sv * o1 + bv) * 8.f;
        float e2 = __expf(sv * o2 + bv) * 8.f;
        float e3 = __expf(sv * o3 + bv) * 8.f;
        float gx = 3.f + 8.f * (float)(p % SSIDE);
        float gy = 3.f + 8.f * (float)(p / SSIDE);
        out[g] = cls;
        out[BATCH * HW + g] = ctr;
        float* bbx = out + 2 * BATCH * HW + (size_t)g * 4;
        bbx[0] = gx - e0;
        bbx[1] = gy - e1;
        bbx[2] = gx + e2;
        bbx[3] = gy + e3;
    }
}

extern "C" void kernel_launch(void* const* d_in, const int* in_sizes, int n_in,
                              void* d_out, int out_size, void* d_ws, size_t ws_size,
                              hipStream_t stream) {
    const float* fm     = (const float*)d_in[0];
    const float* fq     = (const float*)d_in[1];
    const float* cls1_w = (const float*)d_in[2];
    const float* cls1_b = (const float*)d_in[3];
    const float* clsk_w = (const float*)d_in[4];
    const float* clsk_b = (const float*)d_in[5];
    const float* reg1_w = (const float*)d_in[6];
    const float* reg1_b = (const float*)d_in[7];
    const float* regk_w = (const float*)d_in[8];
    const float* regk_b = (const float*)d_in[9];
    const float* w_cls  = (const float*)d_in[10];
    const float* b_cls  = (const float*)d_in[11];
    const float* g_cls  = (const float*)d_in[12];
    const float* be_cls = (const float*)d_in[13];
    const float* w_ctr  = (const float*)d_in[14];
    const float* b_ctr  = (const float*)d_in[15];
    const float* g_ctr  = (const float*)d_in[16];
    const float* be_ctr = (const float*)d_in[17];
    const float* w_off  = (const float*)d_in[18];
    const float* b_off  = (const float*)d_in[19];
    const float* g_off  = (const float*)d_in[20];
    const float* be_off = (const float*)d_in[21];
    const float* si     = (const float*)d_in[22];
    const float* bi     = (const float*)d_in[23];

    char* ws = (char*)d_ws;
    ushort* YBF  = (ushort*)(ws + YBF_OFF);
    ushort* XA   = (ushort*)(ws + XA_OFF);
    ushort* XB   = (ushort*)(ws + XB_OFF);
    ushort* WT0  = (ushort*)(ws + WT0_OFF);
    ushort* WT   = (ushort*)(ws + WT_OFF);
    ushort* FMT  = (ushort*)(ws + FMT_OFF);
    ushort* FM32 = (ushort*)(ws + FM32_OFF);
    ushort* FQB  = (ushort*)(ws + FQB_OFF);
    char*   PART = ws + PART_OFF;

    // --- attention ---
    prep_fm<<<dim3(59, 8), 256, 0, stream>>>(fm, FMT, FM32);
    prep_fq<<<dim3(20), 256, 0, stream>>>(fq, FQB);
    attn_flash<<<dim3(480), 512, 0, stream>>>(FMT, FM32, FQB, PART);
    attn_merge_zero<<<dim3(462), 256, 0, stream>>>(PART, fq, YBF, XA, XB);

    // --- weight prep (one launch) ---
    prep_weights<<<dim3(1152 + 512 * 6), 256, 0, stream>>>(cls1_w, reg1_w, clsk_w, regk_w, WT0, WT);

    // --- conv tower: 1D grid 640 with XCD-chunked remap ---
    conv_gemm<<<dim3(640), 256, 0, stream>>>(YBF, 64, 1, 1, WT0, cls1_b, reg1_b, XA);

    ushort* cur = XA;
    ushort* nxt = XB;
    for (int s = 0; s < 6; s++) {
        int relu_out = (s < 5) ? 1 : 0;
        conv_gemm<<<dim3(640), 256, 0, stream>>>(cur, 256, 0, relu_out,
            WT + (size_t)s * WTL_ELEMS,
            clsk_b + (size_t)s * 256, regk_b + (size_t)s * 256, nxt);
        ushort* tmp = cur; cur = nxt; nxt = tmp;
    }

    heads<<<dim3(79), 256, 0, stream>>>(cur, w_cls, b_cls, g_cls, be_cls,
                                        w_ctr, b_ctr, g_ctr, be_ctr,
                                        w_off, b_off, g_off, be_off, si, bi,
                                        (float*)d_out);
}

// Round 12
// 334.071 us; speedup vs baseline: 1.2414x; 1.0384x over previous
//
#include <hip/hip_runtime.h>
#include <math.h>

#define BATCH 8
#define CCH 20
#define THW 15000
#define HW 625
#define SSIDE 25
#define PHW 729          // 27*27 zero-padded spatial

#define NKEY 15000
#define TPAD 15104      // 59*256, padded key dim
#define NKT 118         // ceil(15000/128) k-tiles of 128
#define NKC 20          // k-chunks of 6 tiles (last gets 4)
#define KCHUNK 6

typedef __attribute__((ext_vector_type(8))) short bf16x8;
typedef __attribute__((ext_vector_type(4))) float f32x4;

// ---- ws layout (byte offsets), NON-ALIASED ----
#define YBF_OFF  0ULL            // 8*729*64*2      = 746,496
#define XA_OFF   746496ULL       // 16*729*256*2    = 5,971,968
#define XB_OFF   6718464ULL      // 16*729*256*2    -> ends 12,690,432
#define WT0_OFF  12690432ULL     // 2*9*256*64*2    = 589,824
#define WT_OFF   13280256ULL     // 6*2*9*256*256*2 = 14,155,776 -> ends 27,436,032
#define WTL_ELEMS 1179648ULL     // 2*9*256*256 ushorts per layer
#define FMT_OFF  27436032ULL     // 8*TPAD*32*2 = 7,733,248
#define FM32_OFF 35169280ULL     // 7,733,248
#define FQB_OFF  42902528ULL     // 327,680
#define PART_OFF 43230208ULL     // 8*5*20*128*48 = 4,915,200 -> ends 48,145,408

__device__ __forceinline__ ushort f2bf(float x) {
    unsigned u = __float_as_uint(x);
    u = (u + 0x7FFFu + ((u >> 16) & 1u)) >> 16;
    return (ushort)u;
}
__device__ __forceinline__ float bf2f(ushort v) {
    return __uint_as_float(((unsigned)v) << 16);
}

// direct global->LDS staging (vmcnt-tracked). LDS dest is wave-uniform base;
// HW writes lane*16B linearly from it. Swizzle achieved by per-lane SOURCE.
__device__ __forceinline__ void gload16(const void* g, void* l) {
    __builtin_amdgcn_global_load_lds((const __attribute__((address_space(1))) void*)g,
                                     (__attribute__((address_space(3))) void*)l, 16, 0, 0);
}

// ===== prep (merged): blocks 0..471 = fm -> fmbT/fmb32; 472..491 = fq -> fqb =====
__global__ __launch_bounds__(256) void prep_fmq(const float* __restrict__ fm,
                                                const float* __restrict__ fq,
                                                ushort* __restrict__ fmbT,
                                                ushort* __restrict__ fmb32,
                                                ushort* __restrict__ fqb) {
    __shared__ ushort sT2[256][34];
    const int bid = blockIdx.x;
    const int tid = threadIdx.x;
    if (bid < 472) {
        const int t0 = (bid % 59) * 256;
        const int b = bid / 59;
        const int t = t0 + tid;
        #pragma unroll 4
        for (int c = 0; c < CCH; c++) {
            float v = (t < NKEY) ? fm[((size_t)b * CCH + c) * THW + t] : 0.f;
            ushort h = f2bf(v);
            sT2[tid][c] = h;
            fmb32[((size_t)b * 32 + c) * TPAD + t] = h;
        }
        #pragma unroll
        for (int cz = CCH; cz < 32; cz++)
            fmb32[((size_t)b * 32 + cz) * TPAD + t] = 0;
        __syncthreads();
        const int g = tid >> 4, j = tid & 15;
        uint* dstb = (uint*)fmbT + ((size_t)b * TPAD + t0) * 16 + j;
        #pragma unroll
        for (int i = 0; i < 16; i++) {
            int r = g + 16 * i;
            uint v = 0;
            if (j < 10) v = *(const uint*)&sT2[r][2 * j];
            dstb[(size_t)r * 16] = v;
        }
    } else {
        int idx = (bid - 472) * 256 + tid;
        if (idx >= BATCH * 640) return;
        int b = idx / 640, q = idx % 640;
        const float qscale = 1.4426950408889634f * 0.04419417382415922f;
        ushort* dst = fqb + (size_t)idx * 32;
        #pragma unroll 4
        for (int c = 0; c < CCH; c++) {
            float v = (q < HW) ? fq[((size_t)b * CCH + c) * HW + q] * qscale : 0.f;
            dst[c] = f2bf(v);
        }
        #pragma unroll
        for (int c = CCH; c < 32; c++) dst[c] = 0;
    }
}

// ===== MFMA flash attention v4: padded sP (R0 layout), single barrier/kt,
// setprio around MFMA clusters. XCD swizzle: 1D grid 480, one b per XCD. =====
__global__ __launch_bounds__(512) void attn_flash(const ushort* __restrict__ fmbT,
                                                  const ushort* __restrict__ fmb32,
                                                  const ushort* __restrict__ fqb,
                                                  char* __restrict__ part) {
    __shared__ __align__(16) ushort sK[2][4096];  // 128 keys x 32ch, 64B rows, XOR(r&3) @16B
    __shared__ __align__(16) ushort sV[2][4096];  // 32ch x 128 keys, 256B rows, XOR(r&7) @16B
    __shared__ __align__(16) ushort sP[8][16][136];  // per-wave 16q x 128k, +8 pad (R0-proven)
    const int tid = threadIdx.x;
    const int wave = tid >> 6, lane = tid & 63;
    const int q16 = lane & 15, quad = lane >> 4;
    // XCD-chunked remap: 480 blocks, 60 per XCD = all blocks of one b
    const int phys = blockIdx.x;
    const int lid = (phys & 7) * 60 + (phys >> 3);
    const int b = lid / 60;
    const int rem = lid - b * 60;
    const int kc = rem / 3;
    const int xq = rem - kc * 3;
    const int qt0 = xq * 2 + (wave >> 2);
    const bool act = (qt0 < 5);
    const int qt = act ? qt0 : 4;
    const int wq = wave & 3;

    bf16x8 Qf[2];
    #pragma unroll
    for (int nf = 0; nf < 2; nf++)
        Qf[nf] = *(const bf16x8*)(fqb + ((size_t)(b * 640 + qt * 128 + wq * 32 + nf * 16 + q16) << 5) + quad * 8);

    f32x4 O[2][2];
    #pragma unroll
    for (int nf = 0; nf < 2; nf++) { O[nf][0] = (f32x4)0.f; O[nf][1] = (f32x4)0.f; }
    float lp0 = 0.f, lp1 = 0.f;
    const f32x4 zz = (f32x4)0.f;

    const int kt0 = kc * KCHUNK;
    const int kt1 = (kt0 + KCHUNK < NKT) ? kt0 + KCHUNK : NKT;

    // staging: 512 threads x 16B = 8KB each for K and V (2 gloads/thread/kt)
    const int rK = tid >> 2, cK = tid & 3;       // sK: row=key (64B), 4 chunks
    const int rV = tid >> 4, cV = tid & 15;      // sV: row=ch (256B), 16 chunks
    const ushort* srcK = fmbT + ((size_t)(b * TPAD + rK) << 5) + ((cK ^ (rK & 3)) << 3);
    const ushort* srcV = fmb32 + (size_t)(b * 32 + rV) * TPAD + ((cV ^ (rV & 7)) << 3);
    auto stage = [&](int kt, int bufi) {
        const int t0s = kt << 7;
        gload16(srcK + ((size_t)t0s << 5), &sK[bufi][wave << 9]);
        gload16(srcV + t0s, &sV[bufi][wave << 9]);
    };

    const int q3 = q16 & 3, q7 = q16 & 7;
    uint* const pBase = (uint*)&sP[wave][q16][0];

    int buf = 0;
    stage(kt0, 0);
    asm volatile("s_waitcnt vmcnt(0)\n\ts_barrier" ::: "memory");
    for (int kt = kt0; kt < kt1; kt++) {
        const bool nl = (kt + 1 < kt1);
        if (nl) stage(kt + 1, buf ^ 1);
        const int t0 = kt << 7;
        const bool tail = (t0 + 128 > NKEY);

        bf16x8 Ak[8], Av[8];
        #pragma unroll
        for (int m = 0; m < 8; m++)
            Ak[m] = *(const bf16x8*)&sK[buf][((m * 16 + q16) << 5) + ((quad ^ q3) << 3)];
        #pragma unroll
        for (int mp = 0; mp < 4; mp++)
            #pragma unroll
            for (int cf = 0; cf < 2; cf++)
                Av[mp * 2 + cf] = *(const bf16x8*)&sV[buf][((cf * 16 + q16) << 7) + (((mp * 4 + quad) ^ q7) << 3)];

        f32x4 S[8][2];
        __builtin_amdgcn_s_setprio(1);
        #pragma unroll
        for (int m = 0; m < 8; m++) {
            S[m][0] = __builtin_amdgcn_mfma_f32_16x16x32_bf16(Ak[m], Qf[0], zz, 0, 0, 0);
            S[m][1] = __builtin_amdgcn_mfma_f32_16x16x32_bf16(Ak[m], Qf[1], zz, 0, 0, 0);
        }
        __builtin_amdgcn_s_setprio(0);

        #pragma unroll
        for (int nf = 0; nf < 2; nf++) {
            float lacc = 0.f;
            #pragma unroll
            for (int m = 0; m < 8; m++) {
                float p[4];
                #pragma unroll
                for (int i = 0; i < 4; i++) {
                    float v = __builtin_amdgcn_exp2f(S[m][nf][i]);
                    if (tail && (t0 + m * 16 + quad * 4 + i >= NKEY)) v = 0.f;
                    p[i] = v;
                }
                lacc += (p[0] + p[1]) + (p[2] + p[3]);
                uint pk0 = __builtin_amdgcn_perm(__float_as_uint(p[1]) + 0x8000u,
                                                 __float_as_uint(p[0]) + 0x8000u, 0x07060302u);
                uint pk1 = __builtin_amdgcn_perm(__float_as_uint(p[3]) + 0x8000u,
                                                 __float_as_uint(p[2]) + 0x8000u, 0x07060302u);
                uint* dst = pBase + m * 8 + quad * 2;
                dst[0] = pk0;
                dst[1] = pk1;
            }
            if (nf == 0) lp0 += lacc; else lp1 += lacc;
            __builtin_amdgcn_s_setprio(1);
            #pragma unroll
            for (int mp = 0; mp < 4; mp++) {
                bf16x8 Bp = *(const bf16x8*)&sP[wave][q16][mp * 32 + quad * 8];
                O[nf][0] = __builtin_amdgcn_mfma_f32_16x16x32_bf16(Av[mp * 2 + 0], Bp, O[nf][0], 0, 0, 0);
                O[nf][1] = __builtin_amdgcn_mfma_f32_16x16x32_bf16(Av[mp * 2 + 1], Bp, O[nf][1], 0, 0, 0);
            }
            __builtin_amdgcn_s_setprio(0);
        }
        if (nl) asm volatile("s_waitcnt vmcnt(0) lgkmcnt(0)\n\ts_barrier" ::: "memory");
        buf ^= 1;
    }

    lp0 += __shfl_xor(lp0, 16); lp0 += __shfl_xor(lp0, 32);
    lp1 += __shfl_xor(lp1, 16); lp1 += __shfl_xor(lp1, 32);

    if (act) {
        #pragma unroll
        for (int nf = 0; nf < 2; nf++) {
            int ql = wq * 32 + nf * 16 + q16;
            size_t rec = ((((size_t)b * 5 + qt) * NKC + kc) * 128 + ql) * 48;
            uint2 pk;
            pk.x = (unsigned)f2bf(O[nf][0][0]) | ((unsigned)f2bf(O[nf][0][1]) << 16);
            pk.y = (unsigned)f2bf(O[nf][0][2]) | ((unsigned)f2bf(O[nf][0][3]) << 16);
            *(uint2*)(part + rec + quad * 8) = pk;
            if (quad == 0) {
                uint2 pk1;
                pk1.x = (unsigned)f2bf(O[nf][1][0]) | ((unsigned)f2bf(O[nf][1][1]) << 16);
                pk1.y = (unsigned)f2bf(O[nf][1][2]) | ((unsigned)f2bf(O[nf][1][3]) << 16);
                *(uint2*)(part + rec + 32) = pk1;
                *(float*)(part + rec + 40) = (nf == 0) ? lp0 : lp1;
            }
        }
    }
}

// merge partials -> YBF (blocks 0..19) + zero halo borders (blocks 20..461)
__device__ __forceinline__ int border_pp(int bi) {
    if (bi < 27) return bi;                   // top row
    if (bi < 54) return 26 * 27 + (bi - 27);  // bottom row
    if (bi < 79) return (bi - 53) * 27;       // left col, rows 1..25
    return (bi - 78) * 27 + 26;               // right col, rows 1..25
}
__global__ __launch_bounds__(256) void attn_merge_zero(const char* __restrict__ part,
                                                       const float* __restrict__ fq,
                                                       ushort* __restrict__ ybf,
                                                       ushort* __restrict__ xa,
                                                       ushort* __restrict__ xb) {
    if (blockIdx.x < 20) {
        int g = blockIdx.x * 256 + threadIdx.x;
        if (g >= BATCH * HW) return;
        int b = g / HW, q = g % HW;
        int qt = q >> 7, ql = q & 127;
        const char* pb = part + ((((size_t)b * 5 + qt) * NKC) * 128 + ql) * 48;
        float L = 0.f;
        float acc[CCH];
        #pragma unroll
        for (int c = 0; c < CCH; c++) acc[c] = 0.f;
        for (int kc = 0; kc < NKC; kc++) {
            const char* rec = pb + (size_t)kc * 128 * 48;
            L += *(const float*)(rec + 40);
            const ushort* av = (const ushort*)rec;
            #pragma unroll
            for (int c = 0; c < CCH; c++) acc[c] += bf2f(av[c]);
        }
        float inv = 1.f / L;
        int pp = (q / 25 + 1) * 27 + (q % 25) + 1;
        ushort* yb = ybf + ((size_t)b * PHW + pp) * 64;
        #pragma unroll
        for (int c = 0; c < CCH; c++) yb[c] = f2bf(acc[c] * inv);
        #pragma unroll
        for (int c = 0; c < CCH; c++) yb[20 + c] = f2bf(fq[((size_t)b * CCH + c) * HW + q]);
        #pragma unroll
        for (int c = 40; c < 64; c++) yb[c] = 0;
    } else {
        int idx = (blockIdx.x - 20) * 256 + threadIdx.x;
        ushort* buf; int cin;
        if (idx < 6656) { buf = ybf; cin = 64; }
        else if (idx < 59904) { idx -= 6656; buf = xa; cin = 256; }
        else if (idx < 113152) { idx -= 59904; buf = xb; cin = 256; }
        else return;
        int nc = cin >> 3;
        int per = 104 * nc;
        int img = idx / per, r = idx - img * per;
        int bi = r / nc, cc = r - bi * nc;
        int pp = border_pp(bi);
        uint4 z = make_uint4(0, 0, 0, 0);
        *(uint4*)&buf[((size_t)img * PHW + pp) * cin + cc * 8] = z;
    }
}

// ===== combined weight prep: blocks 0..1151 = w0; 1152.. = wk (512/layer) ====
__global__ __launch_bounds__(256) void prep_weights(const float* __restrict__ cw1,
                                                    const float* __restrict__ rw1,
                                                    const float* __restrict__ cwk,
                                                    const float* __restrict__ rwk,
                                                    ushort* __restrict__ wt0,
                                                    ushort* __restrict__ wt) {
    int bid = blockIdx.x;
    if (bid < 1152) {
        int idx = bid * 256 + threadIdx.x;
        if (idx >= 2 * 9 * 256 * 64) return;
        int ic = idx & 63;
        int oc = (idx >> 6) & 255;
        int t = idx >> 14;
        int kyx = t % 9;
        int br = t / 9;
        float v = 0.f;
        if (ic < 40) {
            const float* w = br ? rw1 : cw1;
            v = w[((size_t)oc * 40 + ic) * 9 + kyx];
        }
        wt0[idx] = f2bf(v);
    } else {
        int rb = bid - 1152;
        int s = rb >> 9;
        int idx = (rb & 511) * 256 + threadIdx.x;
        if (idx >= 2 * 256 * 256) return;
        int ic = idx & 255;
        int oc = (idx >> 8) & 255;
        int br = idx >> 16;
        const float* w = br ? rwk : cwk;
        const float* src = w + (((size_t)s * 256 + oc) * 256 + ic) * 9;
        ushort* dst = wt + (size_t)s * WTL_ELEMS;
        float v[9];
        #pragma unroll
        for (int k = 0; k < 9; k++) v[k] = src[k];
        #pragma unroll
        for (int k = 0; k < 9; k++)
            dst[(((size_t)(br * 9 + k)) * 256 + oc) * 256 + ic] = f2bf(v[k]);
    }
}

// ======= implicit-im2col GEMM conv v6: B-HALO reuse (R11-verified) =======
__global__ __launch_bounds__(256) void conv_gemm(
    const ushort* __restrict__ xin, int cin, int in_shared, int relu_out,
    const ushort* __restrict__ wt, const float* __restrict__ bias_c,
    const float* __restrict__ bias_r, ushort* __restrict__ xout) {
    __shared__ __align__(16) ushort sA[2][4096];   // 2 x 8KB weight tiles
    __shared__ __align__(16) ushort sBh[2][8192];  // 2 x 16KB halo (128 rows x 64ch)
    const int tid = threadIdx.x;
    const int lane = tid & 63;
    const int wave = tid >> 6;
    const int n16 = lane & 15, quad = lane >> 4;
    const int wm = wave & 1, wn = wave >> 1;
    // XCD-chunked remap (640 % 8 == 0, bijective)
    const int phys = blockIdx.x;
    const int lid = (phys & 7) * 80 + (phys >> 3);
    const int bb = lid / 40;
    const int rr2 = lid - bb * 40;
    const int ot = rr2 & 3, nt = rr2 >> 2;
    const int oc0 = ot * 64;
    const ushort* wbr = wt + (size_t)(bb < 8 ? 0 : 1) * 9 * 256 * cin;
    const float* bias = (bb < 8) ? bias_c : bias_r;
    const ushort* inb = xin + (size_t)(in_shared ? (bb & 7) : bb) * PHW * cin;

    const int l8 = lane >> 3, j8 = lane & 7;
    const int jj = j8 ^ l8;                    // source chunk swizzle (dest r&7 == l8)

    // A staging: wave w owns oc rows [w*16, w*16+16) as two 1KB segments
    const int rA = wave * 16 + l8;
    const ushort* aS0 = wbr + (size_t)(oc0 + rA) * cin + jj * 8;
    const ushort* aS1 = aS0 + (size_t)8 * cin;
    const int segA = wave * 1024;

    // B halo staging: padded base row ppb = pp(p0)-28; thread covers 4 rows
    const int p0 = nt * 64;
    const int ppb = p0 + 2 * (p0 / 25);        // == pp(p0) - 28
    const ushort* bS = inb + (size_t)ppb * cin + jj * 8;

    const int NCH = cin >> 6;                  // 64-ch chunks (1 or 4)

    auto issueA = [&](int ch, int kyx, int buf) {    // 2 loads
        const int aoff = kyx * 256 * cin + ch * 64;
        gload16(aS0 + aoff, &sA[buf][segA]);
        gload16(aS1 + aoff, &sA[buf][segA + 512]);
    };
    auto issueB1 = [&](int ch, int q, int buf) {     // 1 load (1/4 of halo)
        const int rb = (wave * 4 + q) * 8;
        gload16(bS + (size_t)(rb + l8) * cin + ch * 64, &sBh[buf][rb * 64]);
    };

    f32x4 acc00 = (f32x4)0.f, acc01 = (f32x4)0.f;
    f32x4 acc10 = (f32x4)0.f, acc11 = (f32x4)0.f;
    const int arow0 = wm * 32 + n16;
    const int h8 = n16 & 7;
    const int pos0 = p0 + wn * 32 + n16;
    const int pos1 = pos0 + 16;
    const int PR0 = pos0 + 28 + 2 * (pos0 / 25) - ppb;   // halo row of center tap
    const int PR1 = pos1 + 28 + 2 * (pos1 / 25) - ppb;

    auto mfma_tap = [&](const ushort* sa, const ushort* sbh, int d) {
        const int row0 = PR0 + d, row1 = PR1 + d;
        const int m0 = row0 & 7, m1 = row1 & 7;
        #pragma unroll
        for (int ks = 0; ks < 2; ks++) {
            const int cq = ks * 4 + quad;
            bf16x8 a0 = *(const bf16x8*)&sa[arow0 * 64 + ((cq ^ h8) << 3)];
            bf16x8 a1 = *(const bf16x8*)&sa[(arow0 + 16) * 64 + ((cq ^ h8) << 3)];
            bf16x8 b0 = *(const bf16x8*)&sbh[row0 * 64 + ((cq ^ m0) << 3)];
            bf16x8 b1 = *(const bf16x8*)&sbh[row1 * 64 + ((cq ^ m1) << 3)];
            acc00 = __builtin_amdgcn_mfma_f32_16x16x32_bf16(a0, b0, acc00, 0, 0, 0);
            acc01 = __builtin_amdgcn_mfma_f32_16x16x32_bf16(a0, b1, acc01, 0, 0, 0);
            acc10 = __builtin_amdgcn_mfma_f32_16x16x32_bf16(a1, b0, acc10, 0, 0, 0);
            acc11 = __builtin_amdgcn_mfma_f32_16x16x32_bf16(a1, b1, acc11, 0, 0, 0);
        }
    };

    // prologue: halo chunk 0 (4 loads) + A(0,0) (2 loads), drain all
    issueB1(0, 0, 0); issueB1(0, 1, 0); issueB1(0, 2, 0); issueB1(0, 3, 0);
    issueA(0, 0, 0);
    asm volatile("s_waitcnt vmcnt(0)\n\ts_barrier" ::: "memory");

    int itg = 0;
    for (int c = 0; c < NCH; c++) {
        #pragma unroll
        for (int kyx = 0; kyx < 9; kyx++, itg++) {
            if (itg + 1 < NCH * 9) {
                const int nk = (kyx == 8) ? 0 : kyx + 1;
                const int nc = (kyx == 8) ? c + 1 : c;
                issueA(nc, nk, (itg + 1) & 1);
            }
            const bool bpf = (kyx < 4) && (c + 1 < NCH);
            if (bpf) issueB1(c + 1, kyx, (c + 1) & 1);
            const int ky = kyx / 3, kx = kyx % 3;
            mfma_tap(sA[itg & 1], sBh[c & 1], (ky - 1) * 27 + (kx - 1));
            // wait: A(next) must land; one B-halo load may stay in flight
            if (bpf) asm volatile("s_waitcnt vmcnt(1)\n\ts_barrier" ::: "memory");
            else     asm volatile("s_waitcnt vmcnt(0)\n\ts_barrier" ::: "memory");
        }
    }

    f32x4 accs[2][2] = {{acc00, acc01}, {acc10, acc11}};
    #pragma unroll
    for (int mf = 0; mf < 2; mf++) {
        int ocb = oc0 + wm * 32 + mf * 16 + quad * 4;
        float4 bv = *(const float4*)(bias + ocb);
        #pragma unroll
        for (int nf = 0; nf < 2; nf++) {
            int pcol = nt * 64 + wn * 32 + nf * 16 + n16;
            if (pcol >= HW) continue;
            int pp = (pcol / 25 + 1) * 27 + (pcol % 25) + 1;
            f32x4 a = accs[mf][nf];
            float v0 = a[0] + bv.x;
            float v1 = a[1] + bv.y;
            float v2 = a[2] + bv.z;
            float v3 = a[3] + bv.w;
            if (relu_out) {
                v0 = fmaxf(v0, 0.f); v1 = fmaxf(v1, 0.f);
                v2 = fmaxf(v2, 0.f); v3 = fmaxf(v3, 0.f);
            }
            uint2 st;
            st.x = (unsigned)f2bf(v0) | ((unsigned)f2bf(v1) << 16);
            st.y = (unsigned)f2bf(v2) | ((unsigned)f2bf(v3) << 16);
            *(uint2*)(&xout[((size_t)bb * PHW + pp) * 256 + ocb]) = st;
        }
    }
}

// ===== heads v2: 4-way channel split per output, wave handles 16 outputs =====
__global__ __launch_bounds__(256) void heads(const ushort* __restrict__ X,
                                             const float* __restrict__ wcls, const float* __restrict__ bcls,
                                             const float* __restrict__ gcls, const float* __restrict__ becls,
                                             const float* __restrict__ wctr, const float* __restrict__ bctr,
                                             const float* __restrict__ gctr, const float* __restrict__ bectr,
                                             const float* __restrict__ woff, const float* __restrict__ boff,
                                             const float* __restrict__ goff, const float* __restrict__ beoff,
                                             const float* __restrict__ si, const float* __restrict__ bi,
                                             float* __restrict__ out) {
    const int lane = threadIdx.x & 63, wave = threadIdx.x >> 6;
    const int gw = blockIdx.x * 4 + wave;
    const int g = gw * 16 + (lane & 15);
    const int quad = lane >> 4;
    const bool valid = (g < BATCH * HW);
    const int gc = valid ? g : (BATCH * HW - 1);
    const int b = gc / HW, p = gc % HW;
    const int pp = (p / 25 + 1) * 27 + (p % 25) + 1;
    const ushort* fc = X + ((size_t)b * PHW + pp) * 256 + quad * 64;
    const ushort* fr = X + ((size_t)(8 + b) * PHW + pp) * 256 + quad * 64;
    float ac = 0.f, at = 0.f, a0 = 0.f, a1 = 0.f, a2 = 0.f, a3 = 0.f;
    #pragma unroll
    for (int c0 = 0; c0 < 64; c0 += 8) {
        uint4 vc = *(const uint4*)(fc + c0);
        uint4 vr = *(const uint4*)(fr + c0);
        unsigned wc_[4] = {vc.x, vc.y, vc.z, vc.w};
        unsigned wr_[4] = {vr.x, vr.y, vr.z, vr.w};
        #pragma unroll
        for (int j = 0; j < 4; j++) {
            float cl = __uint_as_float(wc_[j] << 16);
            float ch = __uint_as_float(wc_[j] & 0xFFFF0000u);
            float rl = __uint_as_float(wr_[j] << 16);
            float rh = __uint_as_float(wr_[j] & 0xFFFF0000u);
            int c = quad * 64 + c0 + j * 2;
            ac += wcls[c] * cl + wcls[c + 1] * ch;
            at += wctr[c] * cl + wctr[c + 1] * ch;
            a0 += woff[c] * rl + woff[c + 1] * rh;
            a1 += woff[256 + c] * rl + woff[256 + c + 1] * rh;
            a2 += woff[512 + c] * rl + woff[512 + c + 1] * rh;
            a3 += woff[768 + c] * rl + woff[768 + c + 1] * rh;
        }
    }
    // reduce across the 4 channel-quarters (lanes with same lane&15)
    ac += __shfl_xor(ac, 16); at += __shfl_xor(at, 16);
    a0 += __shfl_xor(a0, 16); a1 += __shfl_xor(a1, 16);
    a2 += __shfl_xor(a2, 16); a3 += __shfl_xor(a3, 16);
    ac += __shfl_xor(ac, 32); at += __shfl_xor(at, 32);
    a0 += __shfl_xor(a0, 32); a1 += __shfl_xor(a1, 32);
    a2 += __shfl_xor(a2, 32); a3 += __shfl_xor(a3, 32);
    if (quad == 0 && valid) {
        const float bns = 1.f / sqrtf(1.f + 1e-5f);
        float cls = (ac + bcls[0]) * (gcls[0] * bns) + becls[0];
        float ctr = (at + bctr[0]) * (gctr[0] * bns) + bectr[0];
        float sv = si[0], bv = bi[0];
        float o0 = (a0 + boff[0]) * (goff[0] * bns) + beoff[0];
        float o1 = (a1 + boff[1]) * (goff[1] * bns) + beoff[1];
        float o2 = (a2 + boff[2]) * (goff[2] * bns) + beoff[2];
        float o3 = (a3 + boff[3]) * (goff[3] * bns) + beoff[3];
        float e0 = __expf(sv * o0 + bv) * 8.f;
        float e1 = __expf(sv * o1 + bv) * 8.f;
        float e2 = __expf(sv * o2 + bv) * 8.f;
        float e3 = __expf(sv * o3 + bv) * 8.f;
        float gx = 3.f + 8.f * (float)(p % SSIDE);
        float gy = 3.f + 8.f * (float)(p / SSIDE);
        out[g] = cls;
        out[BATCH * HW + g] = ctr;
        float* bbx = out + 2 * BATCH * HW + (size_t)g * 4;
        bbx[0] = gx - e0;
        bbx[1] = gy - e1;
        bbx[2] = gx + e2;
        bbx[3] = gy + e3;
    }
}

extern "C" void kernel_launch(void* const* d_in, const int* in_sizes, int n_in,
                              void* d_out, int out_size, void* d_ws, size_t ws_size,
                              hipStream_t stream) {
    const float* fm     = (const float*)d_in[0];
    const float* fq     = (const float*)d_in[1];
    const float* cls1_w = (const float*)d_in[2];
    const float* cls1_b = (const float*)d_in[3];
    const float* clsk_w = (const float*)d_in[4];
    const float* clsk_b = (const float*)d_in[5];
    const float* reg1_w = (const float*)d_in[6];
    const float* reg1_b = (const float*)d_in[7];
    const float* regk_w = (const float*)d_in[8];
    const float* regk_b = (const float*)d_in[9];
    const float* w_cls  = (const float*)d_in[10];
    const float* b_cls  = (const float*)d_in[11];
    const float* g_cls  = (const float*)d_in[12];
    const float* be_cls = (const float*)d_in[13];
    const float* w_ctr  = (const float*)d_in[14];
    const float* b_ctr  = (const float*)d_in[15];
    const float* g_ctr  = (const float*)d_in[16];
    const float* be_ctr = (const float*)d_in[17];
    const float* w_off  = (const float*)d_in[18];
    const float* b_off  = (const float*)d_in[19];
    const float* g_off  = (const float*)d_in[20];
    const float* be_off = (const float*)d_in[21];
    const float* si     = (const float*)d_in[22];
    const float* bi     = (const float*)d_in[23];

    char* ws = (char*)d_ws;
    ushort* YBF  = (ushort*)(ws + YBF_OFF);
    ushort* XA   = (ushort*)(ws + XA_OFF);
    ushort* XB   = (ushort*)(ws + XB_OFF);
    ushort* WT0  = (ushort*)(ws + WT0_OFF);
    ushort* WT   = (ushort*)(ws + WT_OFF);
    ushort* FMT  = (ushort*)(ws + FMT_OFF);
    ushort* FM32 = (ushort*)(ws + FM32_OFF);
    ushort* FQB  = (ushort*)(ws + FQB_OFF);
    char*   PART = ws + PART_OFF;

    // --- attention ---
    prep_fmq<<<dim3(492), 256, 0, stream>>>(fm, fq, FMT, FM32, FQB);
    attn_flash<<<dim3(480), 512, 0, stream>>>(FMT, FM32, FQB, PART);
    attn_merge_zero<<<dim3(462), 256, 0, stream>>>(PART, fq, YBF, XA, XB);

    // --- weight prep (one launch) ---
    prep_weights<<<dim3(1152 + 512 * 6), 256, 0, stream>>>(cls1_w, reg1_w, clsk_w, regk_w, WT0, WT);

    // --- conv tower: 1D grid 640 with XCD-chunked remap ---
    conv_gemm<<<dim3(640), 256, 0, stream>>>(YBF, 64, 1, 1, WT0, cls1_b, reg1_b, XA);

    ushort* cur = XA;
    ushort* nxt = XB;
    for (int s = 0; s < 6; s++) {
        int relu_out = (s < 5) ? 1 : 0;
        conv_gemm<<<dim3(640), 256, 0, stream>>>(cur, 256, 0, relu_out,
            WT + (size_t)s * WTL_ELEMS,
            clsk_b + (size_t)s * 256, regk_b + (size_t)s * 256, nxt);
        ushort* tmp = cur; cur = nxt; nxt = tmp;
    }

    heads<<<dim3(79), 256, 0, stream>>>(cur, w_cls, b_cls, g_cls, be_cls,
                                        w_ctr, b_ctr, g_ctr, be_ctr,
                                        w_off, b_off, g_off, be_off, si, bi,
                                        (float*)d_out);
}

// Round 13
// 330.197 us; speedup vs baseline: 1.2559x; 1.0117x over previous
//
#include <hip/hip_runtime.h>
#include <math.h>

#define BATCH 8
#define CCH 20
#define THW 15000
#define HW 625
#define SSIDE 25
#define PHW 729          // 27*27 zero-padded spatial

#define NKEY 15000
#define TPAD 15104      // 59*256, padded key dim
#define NKT 118         // ceil(15000/128) k-tiles of 128
#define NKC 20          // k-chunks of 6 tiles (last gets 4)
#define KCHUNK 6

typedef __attribute__((ext_vector_type(8))) short bf16x8;
typedef __attribute__((ext_vector_type(4))) float f32x4;

// ---- ws layout (byte offsets), NON-ALIASED ----
#define YBF_OFF  0ULL            // 8*729*64*2      = 746,496
#define XA_OFF   746496ULL       // 16*729*256*2    = 5,971,968
#define XB_OFF   6718464ULL      // 16*729*256*2    -> ends 12,690,432
#define WT0_OFF  12690432ULL     // 2*9*256*64*2    = 589,824
#define WT_OFF   13280256ULL     // 6*2*9*256*256*2 = 14,155,776 -> ends 27,436,032
#define WTL_ELEMS 1179648ULL     // 2*9*256*256 ushorts per layer
#define FMT_OFF  27436032ULL     // 8*TPAD*32*2 = 7,733,248
#define FM32_OFF 35169280ULL     // 7,733,248
#define FQB_OFF  42902528ULL     // 327,680
#define PART_OFF 43230208ULL     // 8*5*20*128*48 = 4,915,200 -> ends 48,145,408

__device__ __forceinline__ ushort f2bf(float x) {
    unsigned u = __float_as_uint(x);
    u = (u + 0x7FFFu + ((u >> 16) & 1u)) >> 16;
    return (ushort)u;
}
__device__ __forceinline__ float bf2f(ushort v) {
    return __uint_as_float(((unsigned)v) << 16);
}

// direct global->LDS staging (vmcnt-tracked). LDS dest is wave-uniform base;
// HW writes lane*16B linearly from it. Swizzle achieved by per-lane SOURCE.
__device__ __forceinline__ void gload16(const void* g, void* l) {
    __builtin_amdgcn_global_load_lds((const __attribute__((address_space(1))) void*)g,
                                     (__attribute__((address_space(3))) void*)l, 16, 0, 0);
}

// ===== prep (merged): blocks 0..471 = fm -> fmbT/fmb32; 472..491 = fq -> fqb =====
__global__ __launch_bounds__(256) void prep_fmq(const float* __restrict__ fm,
                                                const float* __restrict__ fq,
                                                ushort* __restrict__ fmbT,
                                                ushort* __restrict__ fmb32,
                                                ushort* __restrict__ fqb) {
    __shared__ ushort sT2[256][34];
    const int bid = blockIdx.x;
    const int tid = threadIdx.x;
    if (bid < 472) {
        const int t0 = (bid % 59) * 256;
        const int b = bid / 59;
        const int t = t0 + tid;
        #pragma unroll 4
        for (int c = 0; c < CCH; c++) {
            float v = (t < NKEY) ? fm[((size_t)b * CCH + c) * THW + t] : 0.f;
            ushort h = f2bf(v);
            sT2[tid][c] = h;
            fmb32[((size_t)b * 32 + c) * TPAD + t] = h;
        }
        #pragma unroll
        for (int cz = CCH; cz < 32; cz++)
            fmb32[((size_t)b * 32 + cz) * TPAD + t] = 0;
        __syncthreads();
        const int g = tid >> 4, j = tid & 15;
        uint* dstb = (uint*)fmbT + ((size_t)b * TPAD + t0) * 16 + j;
        #pragma unroll
        for (int i = 0; i < 16; i++) {
            int r = g + 16 * i;
            uint v = 0;
            if (j < 10) v = *(const uint*)&sT2[r][2 * j];
            dstb[(size_t)r * 16] = v;
        }
    } else {
        int idx = (bid - 472) * 256 + tid;
        if (idx >= BATCH * 640) return;
        int b = idx / 640, q = idx % 640;
        const float qscale = 1.4426950408889634f * 0.04419417382415922f;
        ushort* dst = fqb + (size_t)idx * 32;
        #pragma unroll 4
        for (int c = 0; c < CCH; c++) {
            float v = (q < HW) ? fq[((size_t)b * CCH + c) * HW + q] * qscale : 0.f;
            dst[c] = f2bf(v);
        }
        #pragma unroll
        for (int c = CCH; c < 32; c++) dst[c] = 0;
    }
}

// ===== MFMA flash attention v4 (R12-verified): padded sP, single barrier/kt,
// setprio around MFMA clusters. XCD swizzle: 1D grid 480, one b per XCD. =====
__global__ __launch_bounds__(512) void attn_flash(const ushort* __restrict__ fmbT,
                                                  const ushort* __restrict__ fmb32,
                                                  const ushort* __restrict__ fqb,
                                                  char* __restrict__ part) {
    __shared__ __align__(16) ushort sK[2][4096];  // 128 keys x 32ch, 64B rows, XOR(r&3) @16B
    __shared__ __align__(16) ushort sV[2][4096];  // 32ch x 128 keys, 256B rows, XOR(r&7) @16B
    __shared__ __align__(16) ushort sP[8][16][136];  // per-wave 16q x 128k, +8 pad (R0-proven)
    const int tid = threadIdx.x;
    const int wave = tid >> 6, lane = tid & 63;
    const int q16 = lane & 15, quad = lane >> 4;
    // XCD-chunked remap: 480 blocks, 60 per XCD = all blocks of one b
    const int phys = blockIdx.x;
    const int lid = (phys & 7) * 60 + (phys >> 3);
    const int b = lid / 60;
    const int rem = lid - b * 60;
    const int kc = rem / 3;
    const int xq = rem - kc * 3;
    const int qt0 = xq * 2 + (wave >> 2);
    const bool act = (qt0 < 5);
    const int qt = act ? qt0 : 4;
    const int wq = wave & 3;

    bf16x8 Qf[2];
    #pragma unroll
    for (int nf = 0; nf < 2; nf++)
        Qf[nf] = *(const bf16x8*)(fqb + ((size_t)(b * 640 + qt * 128 + wq * 32 + nf * 16 + q16) << 5) + quad * 8);

    f32x4 O[2][2];
    #pragma unroll
    for (int nf = 0; nf < 2; nf++) { O[nf][0] = (f32x4)0.f; O[nf][1] = (f32x4)0.f; }
    float lp0 = 0.f, lp1 = 0.f;
    const f32x4 zz = (f32x4)0.f;

    const int kt0 = kc * KCHUNK;
    const int kt1 = (kt0 + KCHUNK < NKT) ? kt0 + KCHUNK : NKT;

    // staging: 512 threads x 16B = 8KB each for K and V (2 gloads/thread/kt)
    const int rK = tid >> 2, cK = tid & 3;       // sK: row=key (64B), 4 chunks
    const int rV = tid >> 4, cV = tid & 15;      // sV: row=ch (256B), 16 chunks
    const ushort* srcK = fmbT + ((size_t)(b * TPAD + rK) << 5) + ((cK ^ (rK & 3)) << 3);
    const ushort* srcV = fmb32 + (size_t)(b * 32 + rV) * TPAD + ((cV ^ (rV & 7)) << 3);
    auto stage = [&](int kt, int bufi) {
        const int t0s = kt << 7;
        gload16(srcK + ((size_t)t0s << 5), &sK[bufi][wave << 9]);
        gload16(srcV + t0s, &sV[bufi][wave << 9]);
    };

    const int q3 = q16 & 3, q7 = q16 & 7;
    uint* const pBase = (uint*)&sP[wave][q16][0];

    int buf = 0;
    stage(kt0, 0);
    asm volatile("s_waitcnt vmcnt(0)\n\ts_barrier" ::: "memory");
    for (int kt = kt0; kt < kt1; kt++) {
        const bool nl = (kt + 1 < kt1);
        if (nl) stage(kt + 1, buf ^ 1);
        const int t0 = kt << 7;
        const bool tail = (t0 + 128 > NKEY);

        bf16x8 Ak[8], Av[8];
        #pragma unroll
        for (int m = 0; m < 8; m++)
            Ak[m] = *(const bf16x8*)&sK[buf][((m * 16 + q16) << 5) + ((quad ^ q3) << 3)];
        #pragma unroll
        for (int mp = 0; mp < 4; mp++)
            #pragma unroll
            for (int cf = 0; cf < 2; cf++)
                Av[mp * 2 + cf] = *(const bf16x8*)&sV[buf][((cf * 16 + q16) << 7) + (((mp * 4 + quad) ^ q7) << 3)];

        f32x4 S[8][2];
        __builtin_amdgcn_s_setprio(1);
        #pragma unroll
        for (int m = 0; m < 8; m++) {
            S[m][0] = __builtin_amdgcn_mfma_f32_16x16x32_bf16(Ak[m], Qf[0], zz, 0, 0, 0);
            S[m][1] = __builtin_amdgcn_mfma_f32_16x16x32_bf16(Ak[m], Qf[1], zz, 0, 0, 0);
        }
        __builtin_amdgcn_s_setprio(0);

        #pragma unroll
        for (int nf = 0; nf < 2; nf++) {
            float lacc = 0.f;
            #pragma unroll
            for (int m = 0; m < 8; m++) {
                float p[4];
                #pragma unroll
                for (int i = 0; i < 4; i++) {
                    float v = __builtin_amdgcn_exp2f(S[m][nf][i]);
                    if (tail && (t0 + m * 16 + quad * 4 + i >= NKEY)) v = 0.f;
                    p[i] = v;
                }
                lacc += (p[0] + p[1]) + (p[2] + p[3]);
                uint pk0 = __builtin_amdgcn_perm(__float_as_uint(p[1]) + 0x8000u,
                                                 __float_as_uint(p[0]) + 0x8000u, 0x07060302u);
                uint pk1 = __builtin_amdgcn_perm(__float_as_uint(p[3]) + 0x8000u,
                                                 __float_as_uint(p[2]) + 0x8000u, 0x07060302u);
                uint* dst = pBase + m * 8 + quad * 2;
                dst[0] = pk0;
                dst[1] = pk1;
            }
            if (nf == 0) lp0 += lacc; else lp1 += lacc;
            __builtin_amdgcn_s_setprio(1);
            #pragma unroll
            for (int mp = 0; mp < 4; mp++) {
                bf16x8 Bp = *(const bf16x8*)&sP[wave][q16][mp * 32 + quad * 8];
                O[nf][0] = __builtin_amdgcn_mfma_f32_16x16x32_bf16(Av[mp * 2 + 0], Bp, O[nf][0], 0, 0, 0);
                O[nf][1] = __builtin_amdgcn_mfma_f32_16x16x32_bf16(Av[mp * 2 + 1], Bp, O[nf][1], 0, 0, 0);
            }
            __builtin_amdgcn_s_setprio(0);
        }
        if (nl) asm volatile("s_waitcnt vmcnt(0) lgkmcnt(0)\n\ts_barrier" ::: "memory");
        buf ^= 1;
    }

    lp0 += __shfl_xor(lp0, 16); lp0 += __shfl_xor(lp0, 32);
    lp1 += __shfl_xor(lp1, 16); lp1 += __shfl_xor(lp1, 32);

    if (act) {
        #pragma unroll
        for (int nf = 0; nf < 2; nf++) {
            int ql = wq * 32 + nf * 16 + q16;
            size_t rec = ((((size_t)b * 5 + qt) * NKC + kc) * 128 + ql) * 48;
            uint2 pk;
            pk.x = (unsigned)f2bf(O[nf][0][0]) | ((unsigned)f2bf(O[nf][0][1]) << 16);
            pk.y = (unsigned)f2bf(O[nf][0][2]) | ((unsigned)f2bf(O[nf][0][3]) << 16);
            *(uint2*)(part + rec + quad * 8) = pk;
            if (quad == 0) {
                uint2 pk1;
                pk1.x = (unsigned)f2bf(O[nf][1][0]) | ((unsigned)f2bf(O[nf][1][1]) << 16);
                pk1.y = (unsigned)f2bf(O[nf][1][2]) | ((unsigned)f2bf(O[nf][1][3]) << 16);
                *(uint2*)(part + rec + 32) = pk1;
                *(float*)(part + rec + 40) = (nf == 0) ? lp0 : lp1;
            }
        }
    }
}

// ===== merged epilogue/prep: merge partials (0..19) + zero borders (20..461)
// + weight transposes (462..4685) -- weight work overlaps the merge phase. ===
__device__ __forceinline__ int border_pp(int bi) {
    if (bi < 27) return bi;                   // top row
    if (bi < 54) return 26 * 27 + (bi - 27);  // bottom row
    if (bi < 79) return (bi - 53) * 27;       // left col, rows 1..25
    return (bi - 78) * 27 + 26;               // right col, rows 1..25
}
__global__ __launch_bounds__(256) void merge_zero_weights(
        const char* __restrict__ part, const float* __restrict__ fq,
        ushort* __restrict__ ybf, ushort* __restrict__ xa, ushort* __restrict__ xb,
        const float* __restrict__ cw1, const float* __restrict__ rw1,
        const float* __restrict__ cwk, const float* __restrict__ rwk,
        ushort* __restrict__ wt0, ushort* __restrict__ wt) {
    const int bid = blockIdx.x;
    const int tid = threadIdx.x;
    if (bid < 20) {
        int g = bid * 256 + tid;
        if (g >= BATCH * HW) return;
        int b = g / HW, q = g % HW;
        int qt = q >> 7, ql = q & 127;
        const char* pb = part + ((((size_t)b * 5 + qt) * NKC) * 128 + ql) * 48;
        float L = 0.f;
        float acc[CCH];
        #pragma unroll
        for (int c = 0; c < CCH; c++) acc[c] = 0.f;
        for (int kc = 0; kc < NKC; kc++) {
            const char* rec = pb + (size_t)kc * 128 * 48;
            L += *(const float*)(rec + 40);
            const ushort* av = (const ushort*)rec;
            #pragma unroll
            for (int c = 0; c < CCH; c++) acc[c] += bf2f(av[c]);
        }
        float inv = 1.f / L;
        int pp = (q / 25 + 1) * 27 + (q % 25) + 1;
        ushort* yb = ybf + ((size_t)b * PHW + pp) * 64;
        #pragma unroll
        for (int c = 0; c < CCH; c++) yb[c] = f2bf(acc[c] * inv);
        #pragma unroll
        for (int c = 0; c < CCH; c++) yb[20 + c] = f2bf(fq[((size_t)b * CCH + c) * HW + q]);
        #pragma unroll
        for (int c = 40; c < 64; c++) yb[c] = 0;
    } else if (bid < 462) {
        int idx = (bid - 20) * 256 + tid;
        ushort* buf; int cin;
        if (idx < 6656) { buf = ybf; cin = 64; }
        else if (idx < 59904) { idx -= 6656; buf = xa; cin = 256; }
        else if (idx < 113152) { idx -= 59904; buf = xb; cin = 256; }
        else return;
        int nc = cin >> 3;
        int per = 104 * nc;
        int img = idx / per, r = idx - img * per;
        int bi = r / nc, cc = r - bi * nc;
        int pp = border_pp(bi);
        uint4 z = make_uint4(0, 0, 0, 0);
        *(uint4*)&buf[((size_t)img * PHW + pp) * cin + cc * 8] = z;
    } else if (bid < 1614) {
        int idx = (bid - 462) * 256 + tid;
        if (idx >= 2 * 9 * 256 * 64) return;
        int ic = idx & 63;
        int oc = (idx >> 6) & 255;
        int t = idx >> 14;
        int kyx = t % 9;
        int br = t / 9;
        float v = 0.f;
        if (ic < 40) {
            const float* w = br ? rw1 : cw1;
            v = w[((size_t)oc * 40 + ic) * 9 + kyx];
        }
        wt0[idx] = f2bf(v);
    } else {
        int rb = bid - 1614;
        int s = rb >> 9;
        int idx = (rb & 511) * 256 + tid;
        if (idx >= 2 * 256 * 256) return;
        int ic = idx & 255;
        int oc = (idx >> 8) & 255;
        int br = idx >> 16;
        const float* w = br ? rwk : cwk;
        const float* src = w + (((size_t)s * 256 + oc) * 256 + ic) * 9;
        ushort* dst = wt + (size_t)s * WTL_ELEMS;
        float v[9];
        #pragma unroll
        for (int k = 0; k < 9; k++) v[k] = src[k];
        #pragma unroll
        for (int k = 0; k < 9; k++)
            dst[(((size_t)(br * 9 + k)) * 256 + oc) * 256 + ic] = f2bf(v[k]);
    }
}

// ======= implicit-im2col GEMM conv v6: B-HALO reuse (R11-verified) =======
__global__ __launch_bounds__(256) void conv_gemm(
    const ushort* __restrict__ xin, int cin, int in_shared, int relu_out,
    const ushort* __restrict__ wt, const float* __restrict__ bias_c,
    const float* __restrict__ bias_r, ushort* __restrict__ xout) {
    __shared__ __align__(16) ushort sA[2][4096];   // 2 x 8KB weight tiles
    __shared__ __align__(16) ushort sBh[2][8192];  // 2 x 16KB halo (128 rows x 64ch)
    const int tid = threadIdx.x;
    const int lane = tid & 63;
    const int wave = tid >> 6;
    const int n16 = lane & 15, quad = lane >> 4;
    const int wm = wave & 1, wn = wave >> 1;
    // XCD-chunked remap (640 % 8 == 0, bijective)
    const int phys = blockIdx.x;
    const int lid = (phys & 7) * 80 + (phys >> 3);
    const int bb = lid / 40;
    const int rr2 = lid - bb * 40;
    const int ot = rr2 & 3, nt = rr2 >> 2;
    const int oc0 = ot * 64;
    const ushort* wbr = wt + (size_t)(bb < 8 ? 0 : 1) * 9 * 256 * cin;
    const float* bias = (bb < 8) ? bias_c : bias_r;
    const ushort* inb = xin + (size_t)(in_shared ? (bb & 7) : bb) * PHW * cin;

    const int l8 = lane >> 3, j8 = lane & 7;
    const int jj = j8 ^ l8;                    // source chunk swizzle (dest r&7 == l8)

    // A staging: wave w owns oc rows [w*16, w*16+16) as two 1KB segments
    const int rA = wave * 16 + l8;
    const ushort* aS0 = wbr + (size_t)(oc0 + rA) * cin + jj * 8;
    const ushort* aS1 = aS0 + (size_t)8 * cin;
    const int segA = wave * 1024;

    // B halo staging: padded base row ppb = pp(p0)-28; thread covers 4 rows
    const int p0 = nt * 64;
    const int ppb = p0 + 2 * (p0 / 25);        // == pp(p0) - 28
    const ushort* bS = inb + (size_t)ppb * cin + jj * 8;

    const int NCH = cin >> 6;                  // 64-ch chunks (1 or 4)

    auto issueA = [&](int ch, int kyx, int buf) {    // 2 loads
        const int aoff = kyx * 256 * cin + ch * 64;
        gload16(aS0 + aoff, &sA[buf][segA]);
        gload16(aS1 + aoff, &sA[buf][segA + 512]);
    };
    auto issueB1 = [&](int ch, int q, int buf) {     // 1 load (1/4 of halo)
        const int rb = (wave * 4 + q) * 8;
        gload16(bS + (size_t)(rb + l8) * cin + ch * 64, &sBh[buf][rb * 64]);
    };

    f32x4 acc00 = (f32x4)0.f, acc01 = (f32x4)0.f;
    f32x4 acc10 = (f32x4)0.f, acc11 = (f32x4)0.f;
    const int arow0 = wm * 32 + n16;
    const int h8 = n16 & 7;
    const int pos0 = p0 + wn * 32 + n16;
    const int pos1 = pos0 + 16;
    const int PR0 = pos0 + 28 + 2 * (pos0 / 25) - ppb;   // halo row of center tap
    const int PR1 = pos1 + 28 + 2 * (pos1 / 25) - ppb;

    auto mfma_tap = [&](const ushort* sa, const ushort* sbh, int d) {
        const int row0 = PR0 + d, row1 = PR1 + d;
        const int m0 = row0 & 7, m1 = row1 & 7;
        #pragma unroll
        for (int ks = 0; ks < 2; ks++) {
            const int cq = ks * 4 + quad;
            bf16x8 a0 = *(const bf16x8*)&sa[arow0 * 64 + ((cq ^ h8) << 3)];
            bf16x8 a1 = *(const bf16x8*)&sa[(arow0 + 16) * 64 + ((cq ^ h8) << 3)];
            bf16x8 b0 = *(const bf16x8*)&sbh[row0 * 64 + ((cq ^ m0) << 3)];
            bf16x8 b1 = *(const bf16x8*)&sbh[row1 * 64 + ((cq ^ m1) << 3)];
            acc00 = __builtin_amdgcn_mfma_f32_16x16x32_bf16(a0, b0, acc00, 0, 0, 0);
            acc01 = __builtin_amdgcn_mfma_f32_16x16x32_bf16(a0, b1, acc01, 0, 0, 0);
            acc10 = __builtin_amdgcn_mfma_f32_16x16x32_bf16(a1, b0, acc10, 0, 0, 0);
            acc11 = __builtin_amdgcn_mfma_f32_16x16x32_bf16(a1, b1, acc11, 0, 0, 0);
        }
    };

    // prologue: halo chunk 0 (4 loads) + A(0,0) (2 loads), drain all
    issueB1(0, 0, 0); issueB1(0, 1, 0); issueB1(0, 2, 0); issueB1(0, 3, 0);
    issueA(0, 0, 0);
    asm volatile("s_waitcnt vmcnt(0)\n\ts_barrier" ::: "memory");

    int itg = 0;
    for (int c = 0; c < NCH; c++) {
        #pragma unroll
        for (int kyx = 0; kyx < 9; kyx++, itg++) {
            if (itg + 1 < NCH * 9) {
                const int nk = (kyx == 8) ? 0 : kyx + 1;
                const int nc = (kyx == 8) ? c + 1 : c;
                issueA(nc, nk, (itg + 1) & 1);
            }
            const bool bpf = (kyx < 4) && (c + 1 < NCH);
            if (bpf) issueB1(c + 1, kyx, (c + 1) & 1);
            const int ky = kyx / 3, kx = kyx % 3;
            mfma_tap(sA[itg & 1], sBh[c & 1], (ky - 1) * 27 + (kx - 1));
            // wait: A(next) must land; one B-halo load may stay in flight
            if (bpf) asm volatile("s_waitcnt vmcnt(1)\n\ts_barrier" ::: "memory");
            else     asm volatile("s_waitcnt vmcnt(0)\n\ts_barrier" ::: "memory");
        }
    }

    f32x4 accs[2][2] = {{acc00, acc01}, {acc10, acc11}};
    #pragma unroll
    for (int mf = 0; mf < 2; mf++) {
        int ocb = oc0 + wm * 32 + mf * 16 + quad * 4;
        float4 bv = *(const float4*)(bias + ocb);
        #pragma unroll
        for (int nf = 0; nf < 2; nf++) {
            int pcol = nt * 64 + wn * 32 + nf * 16 + n16;
            if (pcol >= HW) continue;
            int pp = (pcol / 25 + 1) * 27 + (pcol % 25) + 1;
            f32x4 a = accs[mf][nf];
            float v0 = a[0] + bv.x;
            float v1 = a[1] + bv.y;
            float v2 = a[2] + bv.z;
            float v3 = a[3] + bv.w;
            if (relu_out) {
                v0 = fmaxf(v0, 0.f); v1 = fmaxf(v1, 0.f);
                v2 = fmaxf(v2, 0.f); v3 = fmaxf(v3, 0.f);
            }
            uint2 st;
            st.x = (unsigned)f2bf(v0) | ((unsigned)f2bf(v1) << 16);
            st.y = (unsigned)f2bf(v2) | ((unsigned)f2bf(v3) << 16);
            *(uint2*)(&xout[((size_t)bb * PHW + pp) * 256 + ocb]) = st;
        }
    }
}

// ===== heads v2: 4-way channel split per output, wave handles 16 outputs =====
__global__ __launch_bounds__(256) void heads(const ushort* __restrict__ X,
                                             const float* __restrict__ wcls, const float* __restrict__ bcls,
                                             const float* __restrict__ gcls, const float* __restrict__ becls,
                                             const float* __restrict__ wctr, const float* __restrict__ bctr,
                                             const float* __restrict__ gctr, const float* __restrict__ bectr,
                                             const float* __restrict__ woff, const float* __restrict__ boff,
                                             const float* __restrict__ goff, const float* __restrict__ beoff,
                                             const float* __restrict__ si, const float* __restrict__ bi,
                                             float* __restrict__ out) {
    const int lane = threadIdx.x & 63, wave = threadIdx.x >> 6;
    const int gw = blockIdx.x * 4 + wave;
    const int g = gw * 16 + (lane & 15);
    const int quad = lane >> 4;
    const bool valid = (g < BATCH * HW);
    const int gc = valid ? g : (BATCH * HW - 1);
    const int b = gc / HW, p = gc % HW;
    const int pp = (p / 25 + 1) * 27 + (p % 25) + 1;
    const ushort* fc = X + ((size_t)b * PHW + pp) * 256 + quad * 64;
    const ushort* fr = X + ((size_t)(8 + b) * PHW + pp) * 256 + quad * 64;
    float ac = 0.f, at = 0.f, a0 = 0.f, a1 = 0.f, a2 = 0.f, a3 = 0.f;
    #pragma unroll
    for (int c0 = 0; c0 < 64; c0 += 8) {
        uint4 vc = *(const uint4*)(fc + c0);
        uint4 vr = *(const uint4*)(fr + c0);
        unsigned wc_[4] = {vc.x, vc.y, vc.z, vc.w};
        unsigned wr_[4] = {vr.x, vr.y, vr.z, vr.w};
        #pragma unroll
        for (int j = 0; j < 4; j++) {
            float cl = __uint_as_float(wc_[j] << 16);
            float ch = __uint_as_float(wc_[j] & 0xFFFF0000u);
            float rl = __uint_as_float(wr_[j] << 16);
            float rh = __uint_as_float(wr_[j] & 0xFFFF0000u);
            int c = quad * 64 + c0 + j * 2;
            ac += wcls[c] * cl + wcls[c + 1] * ch;
            at += wctr[c] * cl + wctr[c + 1] * ch;
            a0 += woff[c] * rl + woff[c + 1] * rh;
            a1 += woff[256 + c] * rl + woff[256 + c + 1] * rh;
            a2 += woff[512 + c] * rl + woff[512 + c + 1] * rh;
            a3 += woff[768 + c] * rl + woff[768 + c + 1] * rh;
        }
    }
    // reduce across the 4 channel-quarters (lanes with same lane&15)
    ac += __shfl_xor(ac, 16); at += __shfl_xor(at, 16);
    a0 += __shfl_xor(a0, 16); a1 += __shfl_xor(a1, 16);
    a2 += __shfl_xor(a2, 16); a3 += __shfl_xor(a3, 16);
    ac += __shfl_xor(ac, 32); at += __shfl_xor(at, 32);
    a0 += __shfl_xor(a0, 32); a1 += __shfl_xor(a1, 32);
    a2 += __shfl_xor(a2, 32); a3 += __shfl_xor(a3, 32);
    if (quad == 0 && valid) {
        const float bns = 1.f / sqrtf(1.f + 1e-5f);
        float cls = (ac + bcls[0]) * (gcls[0] * bns) + becls[0];
        float ctr = (at + bctr[0]) * (gctr[0] * bns) + bectr[0];
        float sv = si[0], bv = bi[0];
        float o0 = (a0 + boff[0]) * (goff[0] * bns) + beoff[0];
        float o1 = (a1 + boff[1]) * (goff[1] * bns) + beoff[1];
        float o2 = (a2 + boff[2]) * (goff[2] * bns) + beoff[2];
        float o3 = (a3 + boff[3]) * (goff[3] * bns) + beoff[3];
        float e0 = __expf(sv * o0 + bv) * 8.f;
        float e1 = __expf(sv * o1 + bv) * 8.f;
        float e2 = __expf(sv * o2 + bv) * 8.f;
        float e3 = __expf(sv * o3 + bv) * 8.f;
        float gx = 3.f + 8.f * (float)(p % SSIDE);
        float gy = 3.f + 8.f * (float)(p / SSIDE);
        out[g] = cls;
        out[BATCH * HW + g] = ctr;
        float* bbx = out + 2 * BATCH * HW + (size_t)g * 4;
        bbx[0] = gx - e0;
        bbx[1] = gy - e1;
        bbx[2] = gx + e2;
        bbx[3] = gy + e3;
    }
}

extern "C" void kernel_launch(void* const* d_in, const int* in_sizes, int n_in,
                              void* d_out, int out_size, void* d_ws, size_t ws_size,
                              hipStream_t stream) {
    const float* fm     = (const float*)d_in[0];
    const float* fq     = (const float*)d_in[1];
    const float* cls1_w = (const float*)d_in[2];
    const float* cls1_b = (const float*)d_in[3];
    const float* clsk_w = (const float*)d_in[4];
    const float* clsk_b = (const float*)d_in[5];
    const float* reg1_w = (const float*)d_in[6];
    const float* reg1_b = (const float*)d_in[7];
    const float* regk_w = (const float*)d_in[8];
    const float* regk_b = (const float*)d_in[9];
    const float* w_cls  = (const float*)d_in[10];
    const float* b_cls  = (const float*)d_in[11];
    const float* g_cls  = (const float*)d_in[12];
    const float* be_cls = (const float*)d_in[13];
    const float* w_ctr  = (const float*)d_in[14];
    const float* b_ctr  = (const float*)d_in[15];
    const float* g_ctr  = (const float*)d_in[16];
    const float* be_ctr = (const float*)d_in[17];
    const float* w_off  = (const float*)d_in[18];
    const float* b_off  = (const float*)d_in[19];
    const float* g_off  = (const float*)d_in[20];
    const float* be_off = (const float*)d_in[21];
    const float* si     = (const float*)d_in[22];
    const float* bi     = (const float*)d_in[23];

    char* ws = (char*)d_ws;
    ushort* YBF  = (ushort*)(ws + YBF_OFF);
    ushort* XA   = (ushort*)(ws + XA_OFF);
    ushort* XB   = (ushort*)(ws + XB_OFF);
    ushort* WT0  = (ushort*)(ws + WT0_OFF);
    ushort* WT   = (ushort*)(ws + WT_OFF);
    ushort* FMT  = (ushort*)(ws + FMT_OFF);
    ushort* FM32 = (ushort*)(ws + FM32_OFF);
    ushort* FQB  = (ushort*)(ws + FQB_OFF);
    char*   PART = ws + PART_OFF;

    // --- attention ---
    prep_fmq<<<dim3(492), 256, 0, stream>>>(fm, fq, FMT, FM32, FQB);
    attn_flash<<<dim3(480), 512, 0, stream>>>(FMT, FM32, FQB, PART);

    // --- merged: attn merge + halo zero + ALL weight prep (one launch) ---
    merge_zero_weights<<<dim3(4686), 256, 0, stream>>>(PART, fq, YBF, XA, XB,
                                                       cls1_w, reg1_w, clsk_w, regk_w,
                                                       WT0, WT);

    // --- conv tower: 1D grid 640 with XCD-chunked remap ---
    conv_gemm<<<dim3(640), 256, 0, stream>>>(YBF, 64, 1, 1, WT0, cls1_b, reg1_b, XA);

    ushort* cur = XA;
    ushort* nxt = XB;
    for (int s = 0; s < 6; s++) {
        int relu_out = (s < 5) ? 1 : 0;
        conv_gemm<<<dim3(640), 256, 0, stream>>>(cur, 256, 0, relu_out,
            WT + (size_t)s * WTL_ELEMS,
            clsk_b + (size_t)s * 256, regk_b + (size_t)s * 256, nxt);
        ushort* tmp = cur; cur = nxt; nxt = tmp;
    }

    heads<<<dim3(79), 256, 0, stream>>>(cur, w_cls, b_cls, g_cls, be_cls,
                                        w_ctr, b_ctr, g_ctr, be_ctr,
                                        w_off, b_off, g_off, be_off, si, bi,
                                        (float*)d_out);
}

// Round 14
// 302.616 us; speedup vs baseline: 1.3704x; 1.0911x over previous
//
#include <hip/hip_runtime.h>
#include <math.h>

#define BATCH 8
#define CCH 20
#define THW 15000
#define HW 625
#define SSIDE 25
#define PHW 729          // 27*27 zero-padded spatial

#define NKEY 15000
#define TPAD 15104      // 59*256, padded key dim
#define NKT 118         // ceil(15000/128) k-tiles of 128
#define NKC 20          // k-chunks of 6 tiles (last gets 4)
#define KCHUNK 6

typedef __attribute__((ext_vector_type(8))) short bf16x8;
typedef __attribute__((ext_vector_type(4))) float f32x4;

// ---- ws layout (byte offsets), NON-ALIASED ----
#define YBF_OFF  0ULL            // 8*729*64*2      = 746,496
#define XA_OFF   746496ULL       // 16*729*256*2    = 5,971,968
#define XB_OFF   6718464ULL      // 16*729*256*2    -> ends 12,690,432
#define WT0_OFF  12690432ULL     // 2*9*256*64*2    = 589,824
#define WT_OFF   13280256ULL     // 6*2*9*256*256*2 = 14,155,776 -> ends 27,436,032
#define WTL_ELEMS 1179648ULL     // 2*9*256*256 ushorts per layer
#define FMT_OFF  27436032ULL     // 8*TPAD*32*2 = 7,733,248
#define FM32_OFF 35169280ULL     // 7,733,248
#define FQB_OFF  42902528ULL     // 327,680
#define PART_OFF 43230208ULL     // 8*5*20*128*48 = 4,915,200 -> ends 48,145,408

__device__ __forceinline__ ushort f2bf(float x) {
    unsigned u = __float_as_uint(x);
    u = (u + 0x7FFFu + ((u >> 16) & 1u)) >> 16;
    return (ushort)u;
}
__device__ __forceinline__ float bf2f(ushort v) {
    return __uint_as_float(((unsigned)v) << 16);
}

// direct global->LDS staging (vmcnt-tracked). LDS dest is wave-uniform base;
// HW writes lane*16B linearly from it. Swizzle achieved by per-lane SOURCE.
__device__ __forceinline__ void gload16(const void* g, void* l) {
    __builtin_amdgcn_global_load_lds((const __attribute__((address_space(1))) void*)g,
                                     (__attribute__((address_space(3))) void*)l, 16, 0, 0);
}

// ===== prep (merged): blocks 0..471 = fm -> fmbT/fmb32; 472..491 = fq -> fqb =====
__global__ __launch_bounds__(256) void prep_fmq(const float* __restrict__ fm,
                                                const float* __restrict__ fq,
                                                ushort* __restrict__ fmbT,
                                                ushort* __restrict__ fmb32,
                                                ushort* __restrict__ fqb) {
    __shared__ ushort sT2[256][34];
    const int bid = blockIdx.x;
    const int tid = threadIdx.x;
    if (bid < 472) {
        const int t0 = (bid % 59) * 256;
        const int b = bid / 59;
        const int t = t0 + tid;
        #pragma unroll 4
        for (int c = 0; c < CCH; c++) {
            float v = (t < NKEY) ? fm[((size_t)b * CCH + c) * THW + t] : 0.f;
            ushort h = f2bf(v);
            sT2[tid][c] = h;
            fmb32[((size_t)b * 32 + c) * TPAD + t] = h;
        }
        #pragma unroll
        for (int cz = CCH; cz < 32; cz++)
            fmb32[((size_t)b * 32 + cz) * TPAD + t] = 0;
        __syncthreads();
        const int g = tid >> 4, j = tid & 15;
        uint* dstb = (uint*)fmbT + ((size_t)b * TPAD + t0) * 16 + j;
        #pragma unroll
        for (int i = 0; i < 16; i++) {
            int r = g + 16 * i;
            uint v = 0;
            if (j < 10) v = *(const uint*)&sT2[r][2 * j];
            dstb[(size_t)r * 16] = v;
        }
    } else {
        int idx = (bid - 472) * 256 + tid;
        if (idx >= BATCH * 640) return;
        int b = idx / 640, q = idx % 640;
        const float qscale = 1.4426950408889634f * 0.04419417382415922f;
        ushort* dst = fqb + (size_t)idx * 32;
        #pragma unroll 4
        for (int c = 0; c < CCH; c++) {
            float v = (q < HW) ? fq[((size_t)b * CCH + c) * HW + q] * qscale : 0.f;
            dst[c] = f2bf(v);
        }
        #pragma unroll
        for (int c = CCH; c < 32; c++) dst[c] = 0;
    }
}

// ===== MFMA flash attention v4 (R12-verified): padded sP, single barrier/kt,
// setprio around MFMA clusters. XCD swizzle: 1D grid 480, one b per XCD. =====
__global__ __launch_bounds__(512) void attn_flash(const ushort* __restrict__ fmbT,
                                                  const ushort* __restrict__ fmb32,
                                                  const ushort* __restrict__ fqb,
                                                  char* __restrict__ part) {
    __shared__ __align__(16) ushort sK[2][4096];  // 128 keys x 32ch, 64B rows, XOR(r&3) @16B
    __shared__ __align__(16) ushort sV[2][4096];  // 32ch x 128 keys, 256B rows, XOR(r&7) @16B
    __shared__ __align__(16) ushort sP[8][16][136];  // per-wave 16q x 128k, +8 pad (R0-proven)
    const int tid = threadIdx.x;
    const int wave = tid >> 6, lane = tid & 63;
    const int q16 = lane & 15, quad = lane >> 4;
    // XCD-chunked remap: 480 blocks, 60 per XCD = all blocks of one b
    const int phys = blockIdx.x;
    const int lid = (phys & 7) * 60 + (phys >> 3);
    const int b = lid / 60;
    const int rem = lid - b * 60;
    const int kc = rem / 3;
    const int xq = rem - kc * 3;
    const int qt0 = xq * 2 + (wave >> 2);
    const bool act = (qt0 < 5);
    const int qt = act ? qt0 : 4;
    const int wq = wave & 3;

    bf16x8 Qf[2];
    #pragma unroll
    for (int nf = 0; nf < 2; nf++)
        Qf[nf] = *(const bf16x8*)(fqb + ((size_t)(b * 640 + qt * 128 + wq * 32 + nf * 16 + q16) << 5) + quad * 8);

    f32x4 O[2][2];
    #pragma unroll
    for (int nf = 0; nf < 2; nf++) { O[nf][0] = (f32x4)0.f; O[nf][1] = (f32x4)0.f; }
    float lp0 = 0.f, lp1 = 0.f;
    const f32x4 zz = (f32x4)0.f;

    const int kt0 = kc * KCHUNK;
    const int kt1 = (kt0 + KCHUNK < NKT) ? kt0 + KCHUNK : NKT;

    // staging: 512 threads x 16B = 8KB each for K and V (2 gloads/thread/kt)
    const int rK = tid >> 2, cK = tid & 3;       // sK: row=key (64B), 4 chunks
    const int rV = tid >> 4, cV = tid & 15;      // sV: row=ch (256B), 16 chunks
    const ushort* srcK = fmbT + ((size_t)(b * TPAD + rK) << 5) + ((cK ^ (rK & 3)) << 3);
    const ushort* srcV = fmb32 + (size_t)(b * 32 + rV) * TPAD + ((cV ^ (rV & 7)) << 3);
    auto stage = [&](int kt, int bufi) {
        const int t0s = kt << 7;
        gload16(srcK + ((size_t)t0s << 5), &sK[bufi][wave << 9]);
        gload16(srcV + t0s, &sV[bufi][wave << 9]);
    };

    const int q3 = q16 & 3, q7 = q16 & 7;
    uint* const pBase = (uint*)&sP[wave][q16][0];

    int buf = 0;
    stage(kt0, 0);
    asm volatile("s_waitcnt vmcnt(0)\n\ts_barrier" ::: "memory");
    for (int kt = kt0; kt < kt1; kt++) {
        const bool nl = (kt + 1 < kt1);
        if (nl) stage(kt + 1, buf ^ 1);
        const int t0 = kt << 7;
        const bool tail = (t0 + 128 > NKEY);

        bf16x8 Ak[8], Av[8];
        #pragma unroll
        for (int m = 0; m < 8; m++)
            Ak[m] = *(const bf16x8*)&sK[buf][((m * 16 + q16) << 5) + ((quad ^ q3) << 3)];
        #pragma unroll
        for (int mp = 0; mp < 4; mp++)
            #pragma unroll
            for (int cf = 0; cf < 2; cf++)
                Av[mp * 2 + cf] = *(const bf16x8*)&sV[buf][((cf * 16 + q16) << 7) + (((mp * 4 + quad) ^ q7) << 3)];

        f32x4 S[8][2];
        __builtin_amdgcn_s_setprio(1);
        #pragma unroll
        for (int m = 0; m < 8; m++) {
            S[m][0] = __builtin_amdgcn_mfma_f32_16x16x32_bf16(Ak[m], Qf[0], zz, 0, 0, 0);
            S[m][1] = __builtin_amdgcn_mfma_f32_16x16x32_bf16(Ak[m], Qf[1], zz, 0, 0, 0);
        }
        __builtin_amdgcn_s_setprio(0);

        #pragma unroll
        for (int nf = 0; nf < 2; nf++) {
            float lacc = 0.f;
            #pragma unroll
            for (int m = 0; m < 8; m++) {
                float p[4];
                #pragma unroll
                for (int i = 0; i < 4; i++) {
                    float v = __builtin_amdgcn_exp2f(S[m][nf][i]);
                    if (tail && (t0 + m * 16 + quad * 4 + i >= NKEY)) v = 0.f;
                    p[i] = v;
                }
                lacc += (p[0] + p[1]) + (p[2] + p[3]);
                uint pk0 = __builtin_amdgcn_perm(__float_as_uint(p[1]) + 0x8000u,
                                                 __float_as_uint(p[0]) + 0x8000u, 0x07060302u);
                uint pk1 = __builtin_amdgcn_perm(__float_as_uint(p[3]) + 0x8000u,
                                                 __float_as_uint(p[2]) + 0x8000u, 0x07060302u);
                uint* dst = pBase + m * 8 + quad * 2;
                dst[0] = pk0;
                dst[1] = pk1;
            }
            if (nf == 0) lp0 += lacc; else lp1 += lacc;
            __builtin_amdgcn_s_setprio(1);
            #pragma unroll
            for (int mp = 0; mp < 4; mp++) {
                bf16x8 Bp = *(const bf16x8*)&sP[wave][q16][mp * 32 + quad * 8];
                O[nf][0] = __builtin_amdgcn_mfma_f32_16x16x32_bf16(Av[mp * 2 + 0], Bp, O[nf][0], 0, 0, 0);
                O[nf][1] = __builtin_amdgcn_mfma_f32_16x16x32_bf16(Av[mp * 2 + 1], Bp, O[nf][1], 0, 0, 0);
            }
            __builtin_amdgcn_s_setprio(0);
        }
        if (nl) asm volatile("s_waitcnt vmcnt(0) lgkmcnt(0)\n\ts_barrier" ::: "memory");
        buf ^= 1;
    }

    lp0 += __shfl_xor(lp0, 16); lp0 += __shfl_xor(lp0, 32);
    lp1 += __shfl_xor(lp1, 16); lp1 += __shfl_xor(lp1, 32);

    if (act) {
        #pragma unroll
        for (int nf = 0; nf < 2; nf++) {
            int ql = wq * 32 + nf * 16 + q16;
            size_t rec = ((((size_t)b * 5 + qt) * NKC + kc) * 128 + ql) * 48;
            uint2 pk;
            pk.x = (unsigned)f2bf(O[nf][0][0]) | ((unsigned)f2bf(O[nf][0][1]) << 16);
            pk.y = (unsigned)f2bf(O[nf][0][2]) | ((unsigned)f2bf(O[nf][0][3]) << 16);
            *(uint2*)(part + rec + quad * 8) = pk;
            if (quad == 0) {
                uint2 pk1;
                pk1.x = (unsigned)f2bf(O[nf][1][0]) | ((unsigned)f2bf(O[nf][1][1]) << 16);
                pk1.y = (unsigned)f2bf(O[nf][1][2]) | ((unsigned)f2bf(O[nf][1][3]) << 16);
                *(uint2*)(part + rec + 32) = pk1;
                *(float*)(part + rec + 40) = (nf == 0) ? lp0 : lp1;
            }
        }
    }
}

// ===== merged epilogue/prep: merge partials (0..19) + zero borders (20..461)
// + weight transposes (462..4685) -- weight work overlaps the merge phase. ===
__device__ __forceinline__ int border_pp(int bi) {
    if (bi < 27) return bi;                   // top row
    if (bi < 54) return 26 * 27 + (bi - 27);  // bottom row
    if (bi < 79) return (bi - 53) * 27;       // left col, rows 1..25
    return (bi - 78) * 27 + 26;               // right col, rows 1..25
}
__global__ __launch_bounds__(256) void merge_zero_weights(
        const char* __restrict__ part, const float* __restrict__ fq,
        ushort* __restrict__ ybf, ushort* __restrict__ xa, ushort* __restrict__ xb,
        const float* __restrict__ cw1, const float* __restrict__ rw1,
        const float* __restrict__ cwk, const float* __restrict__ rwk,
        ushort* __restrict__ wt0, ushort* __restrict__ wt) {
    const int bid = blockIdx.x;
    const int tid = threadIdx.x;
    if (bid < 20) {
        int g = bid * 256 + tid;
        if (g >= BATCH * HW) return;
        int b = g / HW, q = g % HW;
        int qt = q >> 7, ql = q & 127;
        const char* pb = part + ((((size_t)b * 5 + qt) * NKC) * 128 + ql) * 48;
        float L = 0.f;
        float acc[CCH];
        #pragma unroll
        for (int c = 0; c < CCH; c++) acc[c] = 0.f;
        for (int kc = 0; kc < NKC; kc++) {
            const char* rec = pb + (size_t)kc * 128 * 48;
            L += *(const float*)(rec + 40);
            const ushort* av = (const ushort*)rec;
            #pragma unroll
            for (int c = 0; c < CCH; c++) acc[c] += bf2f(av[c]);
        }
        float inv = 1.f / L;
        int pp = (q / 25 + 1) * 27 + (q % 25) + 1;
        ushort* yb = ybf + ((size_t)b * PHW + pp) * 64;
        #pragma unroll
        for (int c = 0; c < CCH; c++) yb[c] = f2bf(acc[c] * inv);
        #pragma unroll
        for (int c = 0; c < CCH; c++) yb[20 + c] = f2bf(fq[((size_t)b * CCH + c) * HW + q]);
        #pragma unroll
        for (int c = 40; c < 64; c++) yb[c] = 0;
    } else if (bid < 462) {
        int idx = (bid - 20) * 256 + tid;
        ushort* buf; int cin;
        if (idx < 6656) { buf = ybf; cin = 64; }
        else if (idx < 59904) { idx -= 6656; buf = xa; cin = 256; }
        else if (idx < 113152) { idx -= 59904; buf = xb; cin = 256; }
        else return;
        int nc = cin >> 3;
        int per = 104 * nc;
        int img = idx / per, r = idx - img * per;
        int bi = r / nc, cc = r - bi * nc;
        int pp = border_pp(bi);
        uint4 z = make_uint4(0, 0, 0, 0);
        *(uint4*)&buf[((size_t)img * PHW + pp) * cin + cc * 8] = z;
    } else if (bid < 1614) {
        int idx = (bid - 462) * 256 + tid;
        if (idx >= 2 * 9 * 256 * 64) return;
        int ic = idx & 63;
        int oc = (idx >> 6) & 255;
        int t = idx >> 14;
        int kyx = t % 9;
        int br = t / 9;
        float v = 0.f;
        if (ic < 40) {
            const float* w = br ? rw1 : cw1;
            v = w[((size_t)oc * 40 + ic) * 9 + kyx];
        }
        wt0[idx] = f2bf(v);
    } else {
        int rb = bid - 1614;
        int s = rb >> 9;
        int idx = (rb & 511) * 256 + tid;
        if (idx >= 2 * 256 * 256) return;
        int ic = idx & 255;
        int oc = (idx >> 8) & 255;
        int br = idx >> 16;
        const float* w = br ? rwk : cwk;
        const float* src = w + (((size_t)s * 256 + oc) * 256 + ic) * 9;
        ushort* dst = wt + (size_t)s * WTL_ELEMS;
        float v[9];
        #pragma unroll
        for (int k = 0; k < 9; k++) v[k] = src[k];
        #pragma unroll
        for (int k = 0; k < 9; k++)
            dst[(((size_t)(br * 9 + k)) * 256 + oc) * 256 + ic] = f2bf(v[k]);
    }
}

// ======= implicit-im2col GEMM conv v7: B-HALO (single buf) + depth-2 A =======
// sA[3] (24KB) + sBh (16KB) = 40KB -> 4 blocks/CU. A loads issued 2 iters
// ahead; steady-state waits vmcnt(2) (A(i+2) stays in flight across barrier).
// Fully unrolled via template<CIN> so every vmcnt count is a static ledger:
//   prologue: B(0)x4, A(0), A(1) -> vmcnt(2) [B+A(0) done] + bar
//   iter i:   issue A(i+2) -> [trans? vmcnt(2)+bar]
//             mfma(sA[i%3], sBh)
//             kyx==8 & more chunks: vmcnt(2)+bar, issue B(c+1)
//             else if i+1<NIT && !skip: vmcnt(2 or 0 at tail)+bar
//   (iter after a transition skips its end-wait: its start-wait vmcnt(2)
//    already forced A(i+1)+B complete.)
template<int CIN>
__global__ __launch_bounds__(256) void conv_gemm_t(
    const ushort* __restrict__ xin, int in_shared, int relu_out,
    const ushort* __restrict__ wt, const float* __restrict__ bias_c,
    const float* __restrict__ bias_r, ushort* __restrict__ xout) {
    constexpr int NCH = CIN >> 6;
    constexpr int NIT = NCH * 9;
    __shared__ __align__(16) ushort sA[3][4096];   // 3 x 8KB weight tiles
    __shared__ __align__(16) ushort sBh[8192];     // 16KB halo (128 rows x 64ch)
    const int tid = threadIdx.x;
    const int lane = tid & 63;
    const int wave = tid >> 6;
    const int n16 = lane & 15, quad = lane >> 4;
    const int wm = wave & 1, wn = wave >> 1;
    // XCD-chunked remap (640 % 8 == 0, bijective)
    const int phys = blockIdx.x;
    const int lid = (phys & 7) * 80 + (phys >> 3);
    const int bb = lid / 40;
    const int rr2 = lid - bb * 40;
    const int ot = rr2 & 3, nt = rr2 >> 2;
    const int oc0 = ot * 64;
    const ushort* wbr = wt + (size_t)(bb < 8 ? 0 : 1) * 9 * 256 * CIN;
    const float* bias = (bb < 8) ? bias_c : bias_r;
    const ushort* inb = xin + (size_t)(in_shared ? (bb & 7) : bb) * PHW * CIN;

    const int l8 = lane >> 3, j8 = lane & 7;
    const int jj = j8 ^ l8;                    // source chunk swizzle (dest r&7 == l8)

    // A staging: wave w owns oc rows [w*16, w*16+16) as two 1KB segments
    const int rA = wave * 16 + l8;
    const ushort* aS0 = wbr + (size_t)(oc0 + rA) * CIN + jj * 8;
    const ushort* aS1 = aS0 + (size_t)8 * CIN;
    const int segA = wave * 1024;

    // B halo staging: padded base row ppb = pp(p0)-28; thread covers 4 rows
    const int p0 = nt * 64;
    const int ppb = p0 + 2 * (p0 / 25);        // == pp(p0) - 28
    const ushort* bS = inb + (size_t)ppb * CIN + jj * 8;

    auto issueA = [&](int it, int buf) {       // 2 loads; it -> (ch, kyx) static
        const int ch = it / 9, kyx = it % 9;
        const int aoff = kyx * 256 * CIN + ch * 64;
        gload16(aS0 + aoff, &sA[buf][segA]);
        gload16(aS1 + aoff, &sA[buf][segA + 512]);
    };
    auto issueB = [&](int ch) {                // 4 loads (full halo for chunk ch)
        #pragma unroll
        for (int q = 0; q < 4; q++) {
            const int rb = (wave * 4 + q) * 8;
            gload16(bS + (size_t)(rb + l8) * CIN + ch * 64, &sBh[rb * 64]);
        }
    };

    f32x4 acc00 = (f32x4)0.f, acc01 = (f32x4)0.f;
    f32x4 acc10 = (f32x4)0.f, acc11 = (f32x4)0.f;
    const int arow0 = wm * 32 + n16;
    const int h8 = n16 & 7;
    const int pos0 = p0 + wn * 32 + n16;
    const int pos1 = pos0 + 16;
    const int PR0 = pos0 + 28 + 2 * (pos0 / 25) - ppb;   // halo row of center tap
    const int PR1 = pos1 + 28 + 2 * (pos1 / 25) - ppb;

    auto mfma_tap = [&](const ushort* sa, int d) {
        const int row0 = PR0 + d, row1 = PR1 + d;
        const int m0 = row0 & 7, m1 = row1 & 7;
        #pragma unroll
        for (int ks = 0; ks < 2; ks++) {
            const int cq = ks * 4 + quad;
            bf16x8 a0 = *(const bf16x8*)&sa[arow0 * 64 + ((cq ^ h8) << 3)];
            bf16x8 a1 = *(const bf16x8*)&sa[(arow0 + 16) * 64 + ((cq ^ h8) << 3)];
            bf16x8 b0 = *(const bf16x8*)&sBh[row0 * 64 + ((cq ^ m0) << 3)];
            bf16x8 b1 = *(const bf16x8*)&sBh[row1 * 64 + ((cq ^ m1) << 3)];
            acc00 = __builtin_amdgcn_mfma_f32_16x16x32_bf16(a0, b0, acc00, 0, 0, 0);
            acc01 = __builtin_amdgcn_mfma_f32_16x16x32_bf16(a0, b1, acc01, 0, 0, 0);
            acc10 = __builtin_amdgcn_mfma_f32_16x16x32_bf16(a1, b0, acc10, 0, 0, 0);
            acc11 = __builtin_amdgcn_mfma_f32_16x16x32_bf16(a1, b1, acc11, 0, 0, 0);
        }
    };

    // prologue: B(0) x4, A(0)->sA[0], A(1)->sA[1]; wait B+A(0) (A(1) in flight)
    issueB(0);
    issueA(0, 0);
    issueA(1, 1);
    asm volatile("s_waitcnt vmcnt(2)\n\ts_barrier" ::: "memory");

    #pragma unroll
    for (int it = 0; it < NIT; it++) {
        const int kyx = it % 9;
        const int c = it / 9;
        const bool trans_in = (kyx == 0) && (c > 0);          // first iter of a new chunk
        const bool trans_out = (kyx == 8) && (c + 1 < NCH);   // last iter before new chunk
        if (it + 2 < NIT) issueA(it + 2, (it + 2) % 3);
        if (trans_in) {
            // outstanding: A(it+1) x2, B x4, A(it+2) x2 -> vmcnt(2) forces A(it+1)+B
            asm volatile("s_waitcnt vmcnt(2)\n\ts_barrier" ::: "memory");
        }
        mfma_tap(sA[it % 3], ((kyx / 3) - 1) * 27 + ((kyx % 3) - 1));
        if (trans_out) {
            // A(it+1) must land; all waves must finish reading sBh before reload
            asm volatile("s_waitcnt vmcnt(2)\n\ts_barrier" ::: "memory");
            issueB(c + 1);
        } else if (!trans_in && it + 1 < NIT) {
            if (it + 2 < NIT)
                asm volatile("s_waitcnt vmcnt(2)\n\ts_barrier" ::: "memory");
            else
                asm volatile("s_waitcnt vmcnt(0)\n\ts_barrier" ::: "memory");
        }
        // trans_in iters skip the end wait: their start wait already forced
        // A(it+1) complete, and no LDS hazard is introduced before next iter.
    }

    f32x4 accs[2][2] = {{acc00, acc01}, {acc10, acc11}};
    #pragma unroll
    for (int mf = 0; mf < 2; mf++) {
        int ocb = oc0 + wm * 32 + mf * 16 + quad * 4;
        float4 bv = *(const float4*)(bias + ocb);
        #pragma unroll
        for (int nf = 0; nf < 2; nf++) {
            int pcol = nt * 64 + wn * 32 + nf * 16 + n16;
            if (pcol >= HW) continue;
            int pp = (pcol / 25 + 1) * 27 + (pcol % 25) + 1;
            f32x4 a = accs[mf][nf];
            float v0 = a[0] + bv.x;
            float v1 = a[1] + bv.y;
            float v2 = a[2] + bv.z;
            float v3 = a[3] + bv.w;
            if (relu_out) {
                v0 = fmaxf(v0, 0.f); v1 = fmaxf(v1, 0.f);
                v2 = fmaxf(v2, 0.f); v3 = fmaxf(v3, 0.f);
            }
            uint2 st;
            st.x = (unsigned)f2bf(v0) | ((unsigned)f2bf(v1) << 16);
            st.y = (unsigned)f2bf(v2) | ((unsigned)f2bf(v3) << 16);
            *(uint2*)(&xout[((size_t)bb * PHW + pp) * 256 + ocb]) = st;
        }
    }
}

// ===== heads v2: 4-way channel split per output, wave handles 16 outputs =====
__global__ __launch_bounds__(256) void heads(const ushort* __restrict__ X,
                                             const float* __restrict__ wcls, const float* __restrict__ bcls,
                                             const float* __restrict__ gcls, const float* __restrict__ becls,
                                             const float* __restrict__ wctr, const float* __restrict__ bctr,
                                             const float* __restrict__ gctr, const float* __restrict__ bectr,
                                             const float* __restrict__ woff, const float* __restrict__ boff,
                                             const float* __restrict__ goff, const float* __restrict__ beoff,
                                             const float* __restrict__ si, const float* __restrict__ bi,
                                             float* __restrict__ out) {
    const int lane = threadIdx.x & 63, wave = threadIdx.x >> 6;
    const int gw = blockIdx.x * 4 + wave;
    const int g = gw * 16 + (lane & 15);
    const int quad = lane >> 4;
    const bool valid = (g < BATCH * HW);
    const int gc = valid ? g : (BATCH * HW - 1);
    const int b = gc / HW, p = gc % HW;
    const int pp = (p / 25 + 1) * 27 + (p % 25) + 1;
    const ushort* fc = X + ((size_t)b * PHW + pp) * 256 + quad * 64;
    const ushort* fr = X + ((size_t)(8 + b) * PHW + pp) * 256 + quad * 64;
    float ac = 0.f, at = 0.f, a0 = 0.f, a1 = 0.f, a2 = 0.f, a3 = 0.f;
    #pragma unroll
    for (int c0 = 0; c0 < 64; c0 += 8) {
        uint4 vc = *(const uint4*)(fc + c0);
        uint4 vr = *(const uint4*)(fr + c0);
        unsigned wc_[4] = {vc.x, vc.y, vc.z, vc.w};
        unsigned wr_[4] = {vr.x, vr.y, vr.z, vr.w};
        #pragma unroll
        for (int j = 0; j < 4; j++) {
            float cl = __uint_as_float(wc_[j] << 16);
            float ch = __uint_as_float(wc_[j] & 0xFFFF0000u);
            float rl = __uint_as_float(wr_[j] << 16);
            float rh = __uint_as_float(wr_[j] & 0xFFFF0000u);
            int c = quad * 64 + c0 + j * 2;
            ac += wcls[c] * cl + wcls[c + 1] * ch;
            at += wctr[c] * cl + wctr[c + 1] * ch;
            a0 += woff[c] * rl + woff[c + 1] * rh;
            a1 += woff[256 + c] * rl + woff[256 + c + 1] * rh;
            a2 += woff[512 + c] * rl + woff[512 + c + 1] * rh;
            a3 += woff[768 + c] * rl + woff[768 + c + 1] * rh;
        }
    }
    // reduce across the 4 channel-quarters (lanes with same lane&15)
    ac += __shfl_xor(ac, 16); at += __shfl_xor(at, 16);
    a0 += __shfl_xor(a0, 16); a1 += __shfl_xor(a1, 16);
    a2 += __shfl_xor(a2, 16); a3 += __shfl_xor(a3, 16);
    ac += __shfl_xor(ac, 32); at += __shfl_xor(at, 32);
    a0 += __shfl_xor(a0, 32); a1 += __shfl_xor(a1, 32);
    a2 += __shfl_xor(a2, 32); a3 += __shfl_xor(a3, 32);
    if (quad == 0 && valid) {
        const float bns = 1.f / sqrtf(1.f + 1e-5f);
        float cls = (ac + bcls[0]) * (gcls[0] * bns) + becls[0];
        float ctr = (at + bctr[0]) * (gctr[0] * bns) + bectr[0];
        float sv = si[0], bv = bi[0];
        float o0 = (a0 + boff[0]) * (goff[0] * bns) + beoff[0];
        float o1 = (a1 + boff[1]) * (goff[1] * bns) + beoff[1];
        float o2 = (a2 + boff[2]) * (goff[2] * bns) + beoff[2];
        float o3 = (a3 + boff[3]) * (goff[3] * bns) + beoff[3];
        float e0 = __expf(sv * o0 + bv) * 8.f;
        float e1 = __expf(sv * o1 + bv) * 8.f;
        float e2 = __expf(sv * o2 + bv) * 8.f;
        float e3 = __expf(sv * o3 + bv) * 8.f;
        float gx = 3.f + 8.f * (float)(p % SSIDE);
        float gy = 3.f + 8.f * (float)(p / SSIDE);
        out[g] = cls;
        out[BATCH * HW + g] = ctr;
        float* bbx = out + 2 * BATCH * HW + (size_t)g * 4;
        bbx[0] = gx - e0;
        bbx[1] = gy - e1;
        bbx[2] = gx + e2;
        bbx[3] = gy + e3;
    }
}

extern "C" void kernel_launch(void* const* d_in, const int* in_sizes, int n_in,
                              void* d_out, int out_size, void* d_ws, size_t ws_size,
                              hipStream_t stream) {
    const float* fm     = (const float*)d_in[0];
    const float* fq     = (const float*)d_in[1];
    const float* cls1_w = (const float*)d_in[2];
    const float* cls1_b = (const float*)d_in[3];
    const float* clsk_w = (const float*)d_in[4];
    const float* clsk_b = (const float*)d_in[5];
    const float* reg1_w = (const float*)d_in[6];
    const float* reg1_b = (const float*)d_in[7];
    const float* regk_w = (const float*)d_in[8];
    const float* regk_b = (const float*)d_in[9];
    const float* w_cls  = (const float*)d_in[10];
    const float* b_cls  = (const float*)d_in[11];
    const float* g_cls  = (const float*)d_in[12];
    const float* be_cls = (const float*)d_in[13];
    const float* w_ctr  = (const float*)d_in[14];
    const float* b_ctr  = (const float*)d_in[15];
    const float* g_ctr  = (const float*)d_in[16];
    const float* be_ctr = (const float*)d_in[17];
    const float* w_off  = (const float*)d_in[18];
    const float* b_off  = (const float*)d_in[19];
    const float* g_off  = (const float*)d_in[20];
    const float* be_off = (const float*)d_in[21];
    const float* si     = (const float*)d_in[22];
    const float* bi     = (const float*)d_in[23];

    char* ws = (char*)d_ws;
    ushort* YBF  = (ushort*)(ws + YBF_OFF);
    ushort* XA   = (ushort*)(ws + XA_OFF);
    ushort* XB   = (ushort*)(ws + XB_OFF);
    ushort* WT0  = (ushort*)(ws + WT0_OFF);
    ushort* WT   = (ushort*)(ws + WT_OFF);
    ushort* FMT  = (ushort*)(ws + FMT_OFF);
    ushort* FM32 = (ushort*)(ws + FM32_OFF);
    ushort* FQB  = (ushort*)(ws + FQB_OFF);
    char*   PART = ws + PART_OFF;

    // --- attention ---
    prep_fmq<<<dim3(492), 256, 0, stream>>>(fm, fq, FMT, FM32, FQB);
    attn_flash<<<dim3(480), 512, 0, stream>>>(FMT, FM32, FQB, PART);

    // --- merged: attn merge + halo zero + ALL weight prep (one launch) ---
    merge_zero_weights<<<dim3(4686), 256, 0, stream>>>(PART, fq, YBF, XA, XB,
                                                       cls1_w, reg1_w, clsk_w, regk_w,
                                                       WT0, WT);

    // --- conv tower: 1D grid 640 with XCD-chunked remap ---
    conv_gemm_t<64><<<dim3(640), 256, 0, stream>>>(YBF, 1, 1, WT0, cls1_b, reg1_b, XA);

    ushort* cur = XA;
    ushort* nxt = XB;
    for (int s = 0; s < 6; s++) {
        int relu_out = (s < 5) ? 1 : 0;
        conv_gemm_t<256><<<dim3(640), 256, 0, stream>>>(cur, 0, relu_out,
            WT + (size_t)s * WTL_ELEMS,
            clsk_b + (size_t)s * 256, regk_b + (size_t)s * 256, nxt);
        ushort* tmp = cur; cur = nxt; nxt = tmp;
    }

    heads<<<dim3(79), 256, 0, stream>>>(cur, w_cls, b_cls, g_cls, be_cls,
                                        w_ctr, b_ctr, g_ctr, be_ctr,
                                        w_off, b_off, g_off, be_off, si, bi,
                                        (float*)d_out);
}